// Round 1
// baseline (1801.756 us; speedup 1.0000x reference)
//
#include <hip/hip_runtime.h>
#include <math.h>

#define CIN  64
#define CI   16
#define HH   256
#define WWD  256
#define KS   7
#define STR  4
#define LH   64
#define LWD  64
#define LL   4096
#define DIN  784
#define DOUT 196
#define NB   2

// ---------------- conv3x3 (g) + conv1x1 (theta), 64ch -> 16ch, pad 1 / 0 ----
__global__ void k_conv(const float* __restrict__ b,
                       const float* __restrict__ g_w, const float* __restrict__ g_b,
                       const float* __restrict__ th_w, const float* __restrict__ th_b,
                       float* __restrict__ b1, float* __restrict__ b2) {
    __shared__ float wg[64 * 9 * 16];  // [ci][t][co]
    __shared__ float wt[64 * 16];      // [ci][co]
    int tid = threadIdx.x;
    for (int i = tid; i < 64 * 9 * 16; i += 256) {
        int co = i & 15; int rest = i >> 4; int t = rest % 9; int ci = rest / 9;
        wg[i] = g_w[(co * 64 + ci) * 9 + t];
    }
    for (int i = tid; i < 64 * 16; i += 256) {
        int co = i & 15; int ci = i >> 4;
        wt[i] = th_w[co * 64 + ci];
    }
    __syncthreads();
    int n = blockIdx.x >> 8;
    int p = ((blockIdx.x & 255) << 8) + tid;   // pixel 0..65535
    int y = p >> 8, x = p & 255;
    float acc1[16], acc2[16];
#pragma unroll
    for (int co = 0; co < 16; co++) { acc1[co] = g_b[co]; acc2[co] = th_b[co]; }
    const float* bn = b + (size_t)n * 64 * 65536;
    for (int ci = 0; ci < 64; ci++) {
        const float* bc = bn + ci * 65536;
#pragma unroll
        for (int dy = 0; dy < 3; dy++) {
            int yy = y + dy - 1;
            if (yy < 0 || yy > 255) continue;
#pragma unroll
            for (int dx = 0; dx < 3; dx++) {
                int xx = x + dx - 1;
                if (xx < 0 || xx > 255) continue;
                float v = bc[yy * 256 + xx];
                int t = dy * 3 + dx;
#pragma unroll
                for (int co = 0; co < 16; co++) acc1[co] += v * wg[(ci * 9 + t) * 16 + co];
                if (dy == 1 && dx == 1) {
#pragma unroll
                    for (int co = 0; co < 16; co++) acc2[co] += v * wt[ci * 16 + co];
                }
            }
        }
    }
    float* o1 = b1 + (size_t)n * 16 * 65536;
    float* o2 = b2 + (size_t)n * 16 * 65536;
#pragma unroll
    for (int co = 0; co < 16; co++) { o1[co * 65536 + p] = acc1[co]; o2[co * 65536 + p] = acc2[co]; }
}

// ---------------- thr: 7x7 stride-4 conv of padded b, 1 out channel ---------
__global__ void k_thr(const float* __restrict__ b, const float* __restrict__ thr_w,
                      const float* __restrict__ thr_b, float* __restrict__ thr) {
    __shared__ float w[64 * 49];
    int tid = threadIdx.x;
    for (int i = tid; i < 64 * 49; i += 256) w[i] = thr_w[i];
    __syncthreads();
    int g = blockIdx.x * 256 + tid;   // 0..8191
    int n = g >> 12; int l = g & 4095;
    int lh = l >> 6, lw = l & 63;
    float acc = thr_b[0];
    const float* bn = b + (size_t)n * 64 * 65536;
    for (int ci = 0; ci < 64; ci++) {
        const float* bc = bn + ci * 65536;
        for (int dy = 0; dy < 7; dy++) {
            int y = lh * 4 + dy - 1;
            if (y < 0 || y > 255) continue;
            for (int dx = 0; dx < 7; dx++) {
                int x = lw * 4 + dx - 1;
                if (x < 0 || x > 255) continue;
                acc += bc[y * 256 + x] * w[ci * 49 + dy * 7 + dx];
            }
        }
    }
    thr[g] = acc;
}

// ---------------- patch extraction of b1 and b2 -> P, pi --------------------
__global__ void k_patches(const float* __restrict__ b1, const float* __restrict__ b2,
                          float* __restrict__ P, float* __restrict__ pi) {
    size_t e = (size_t)blockIdx.x * 256 + threadIdx.x;
    size_t total = (size_t)NB * LL * DIN;
    if (e >= total) return;
    int d = (int)(e % DIN); size_t r = e / DIN;
    int l = (int)(r & 4095); int n = (int)(r >> 12);
    int ci = d / 49; int t = d % 49; int dy = t / 7; int dx = t % 7;
    int lh = l >> 6, lw = l & 63;
    int y = lh * 4 + dy - 1, x = lw * 4 + dx - 1;
    float v1 = 0.f, v2 = 0.f;
    if (y >= 0 && y < 256 && x >= 0 && x < 256) {
        size_t idx = ((size_t)(n * 16 + ci) * 256 + y) * 256 + x;
        v1 = b1[idx]; v2 = b2[idx];
    }
    P[e] = v1; pi[e] = v2;
}

// ---------------- FC GEMM: wif = relu(P @ fc1^T + b1), xif same with fc2 ----
__global__ void k_fcgemm(const float* __restrict__ P,
                         const float* __restrict__ fc1_w, const float* __restrict__ fc1_b,
                         const float* __restrict__ fc2_w, const float* __restrict__ fc2_b,
                         float* __restrict__ wif, float* __restrict__ xif) {
    __shared__ float A_s[16][64], W1_s[16][64], W2_s[16][64];
    int tid = threadIdx.x;
    int tx = tid & 15, ty = tid >> 4;
    int li = tid >> 2, lq = tid & 3;
    int i0 = blockIdx.x * 64, o0 = blockIdx.y * 64;
    float acc1[4][4] = {{0.f}}, acc2[4][4] = {{0.f}};
    bool wvalid = (o0 + li) < DOUT;
    const float* aptr = P + (size_t)(i0 + li) * DIN + lq * 4;
    const float* w1p = fc1_w + (size_t)(o0 + li) * DIN + lq * 4;
    const float* w2p = fc2_w + (size_t)(o0 + li) * DIN + lq * 4;
    for (int k0 = 0; k0 < DIN; k0 += 16) {
        float4 av = *(const float4*)(aptr + k0);
        float4 w1v = make_float4(0, 0, 0, 0), w2v = make_float4(0, 0, 0, 0);
        if (wvalid) { w1v = *(const float4*)(w1p + k0); w2v = *(const float4*)(w2p + k0); }
        __syncthreads();
        int lq4 = lq * 4;
        A_s[lq4 + 0][li] = av.x; A_s[lq4 + 1][li] = av.y; A_s[lq4 + 2][li] = av.z; A_s[lq4 + 3][li] = av.w;
        W1_s[lq4 + 0][li] = w1v.x; W1_s[lq4 + 1][li] = w1v.y; W1_s[lq4 + 2][li] = w1v.z; W1_s[lq4 + 3][li] = w1v.w;
        W2_s[lq4 + 0][li] = w2v.x; W2_s[lq4 + 1][li] = w2v.y; W2_s[lq4 + 2][li] = w2v.z; W2_s[lq4 + 3][li] = w2v.w;
        __syncthreads();
#pragma unroll
        for (int kk = 0; kk < 16; kk++) {
            float4 a = *(const float4*)&A_s[kk][ty * 4];
            float4 w1 = *(const float4*)&W1_s[kk][tx * 4];
            float4 w2 = *(const float4*)&W2_s[kk][tx * 4];
            float aa[4] = {a.x, a.y, a.z, a.w};
            float b1a[4] = {w1.x, w1.y, w1.z, w1.w};
            float b2a[4] = {w2.x, w2.y, w2.z, w2.w};
#pragma unroll
            for (int u = 0; u < 4; u++)
#pragma unroll
                for (int v = 0; v < 4; v++) { acc1[u][v] += aa[u] * b1a[v]; acc2[u][v] += aa[u] * b2a[v]; }
        }
    }
#pragma unroll
    for (int u = 0; u < 4; u++) {
        int row = i0 + ty * 4 + u;
#pragma unroll
        for (int v = 0; v < 4; v++) {
            int col = o0 + tx * 4 + v;
            if (col < DOUT) {
                wif[(size_t)row * DOUT + col] = fmaxf(acc1[u][v] + fc1_b[col], 0.f);
                xif[(size_t)row * DOUT + col] = fmaxf(acc2[u][v] + fc2_b[col], 0.f);
            }
        }
    }
}

// ---------------- score[n][l][m] = wif[n][l] . xif[n][m]  (K=196) -----------
__global__ void k_score(const float* __restrict__ wif, const float* __restrict__ xif,
                        float* __restrict__ score) {
    __shared__ float A_s[16][64], B_s[16][64];
    int n = blockIdx.z;
    int l0 = blockIdx.x * 64, m0 = blockIdx.y * 64;
    int tid = threadIdx.x, tx = tid & 15, ty = tid >> 4, li = tid >> 2, lq = tid & 3;
    const float* A = wif + (size_t)n * LL * DOUT;
    const float* B = xif + (size_t)n * LL * DOUT;
    float acc[4][4] = {{0.f}};
    for (int k0 = 0; k0 < DOUT; k0 += 16) {
        int kc = k0 + lq * 4;
        float4 av = make_float4(0, 0, 0, 0), bv = make_float4(0, 0, 0, 0);
        if (kc < DOUT) {
            av = *(const float4*)&A[(size_t)(l0 + li) * DOUT + kc];
            bv = *(const float4*)&B[(size_t)(m0 + li) * DOUT + kc];
        }
        __syncthreads();
        int lq4 = lq * 4;
        A_s[lq4 + 0][li] = av.x; A_s[lq4 + 1][li] = av.y; A_s[lq4 + 2][li] = av.z; A_s[lq4 + 3][li] = av.w;
        B_s[lq4 + 0][li] = bv.x; B_s[lq4 + 1][li] = bv.y; B_s[lq4 + 2][li] = bv.z; B_s[lq4 + 3][li] = bv.w;
        __syncthreads();
#pragma unroll
        for (int kk = 0; kk < 16; kk++) {
            float4 a = *(const float4*)&A_s[kk][ty * 4];
            float4 b = *(const float4*)&B_s[kk][tx * 4];
            float aa[4] = {a.x, a.y, a.z, a.w};
            float bb[4] = {b.x, b.y, b.z, b.w};
#pragma unroll
            for (int u = 0; u < 4; u++)
#pragma unroll
                for (int v = 0; v < 4; v++) acc[u][v] += aa[u] * bb[v];
        }
    }
    float* srow = score + ((size_t)n * LL + l0) * LL + m0;
#pragma unroll
    for (int u = 0; u < 4; u++) {
        float4 v = make_float4(acc[u][0], acc[u][1], acc[u][2], acc[u][3]);
        *(float4*)&srow[(size_t)(ty * 4 + u) * LL + tx * 4] = v;
    }
}

// ---------------- per-row softmax stats: M = SCALE*max(mask*s), invD --------
__global__ void k_rowstats(const float* __restrict__ score, const float* __restrict__ thr,
                           float* __restrict__ rowM, float* __restrict__ rowD) {
    __shared__ float red[256], red2[256];
    int row = blockIdx.x;
    int tid = threadIdx.x;
    const float* s = score + (size_t)row * LL;
    float t = thr[row];
    float mx = 0.f;
    for (int m = tid; m < LL; m += 256) {
        float v = s[m];
        float g = (v >= t) ? v : 0.f;
        mx = fmaxf(mx, g);
    }
    red[tid] = mx; __syncthreads();
    for (int st = 128; st > 0; st >>= 1) {
        if (tid < st) red[tid] = fmaxf(red[tid], red[tid + st]);
        __syncthreads();
    }
    float M = 10.f * red[0];
    __syncthreads();
    float s2 = 0.f; float n0 = 0.f;
    for (int m = tid; m < LL; m += 256) {
        float v = s[m];
        if (v >= t) s2 += expf(10.f * v - M); else n0 += 1.f;
    }
    red[tid] = s2; red2[tid] = n0; __syncthreads();
    for (int st = 128; st > 0; st >>= 1) {
        if (tid < st) { red[tid] += red[tid + st]; red2[tid] += red2[tid + st]; }
        __syncthreads();
    }
    if (tid == 0) {
        float S2 = red[0], N0 = red2[0];
        float D = S2 + 1e-8f * (S2 + N0 * expf(-M));
        rowM[row] = M;
        rowD[row] = 1.f / D;
    }
}

// ---------------- transform score -> attn weights in place ------------------
__global__ void k_wxform(float4* __restrict__ s4, const float* __restrict__ thr,
                         const float* __restrict__ rowM, const float* __restrict__ rowD) {
    size_t i = (size_t)blockIdx.x * 256 + threadIdx.x;   // 8,388,608 float4s
    int row = (int)(i >> 10);
    float t = thr[row], M = rowM[row], iD = rowD[row];
    float4 v = s4[i];
    v.x = (v.x >= t) ? expf(10.f * v.x - M) * iD : 0.f;
    v.y = (v.y >= t) ? expf(10.f * v.y - M) * iD : 0.f;
    v.z = (v.z >= t) ? expf(10.f * v.z - M) * iD : 0.f;
    v.w = (v.w >= t) ? expf(10.f * v.w - M) * iD : 0.f;
    s4[i] = v;
}

// ---------------- agg = attn @ pi  (K = 4096) -------------------------------
__global__ void k_agg(const float* __restrict__ w, const float* __restrict__ pi,
                      float* __restrict__ agg) {
    __shared__ float A_s[16][64], B_s[16][64];
    int n = blockIdx.z;
    int l0 = blockIdx.x * 64, d0 = blockIdx.y * 64;
    int tid = threadIdx.x, tx = tid & 15, ty = tid >> 4;
    int li = tid >> 2, lq = tid & 3;
    int mm = tid >> 4, dq = tid & 15;
    const float* A = w + (size_t)n * LL * LL;
    const float* B = pi + (size_t)n * LL * DIN;
    float acc[4][4] = {{0.f}};
    int dc = d0 + dq * 4;
    bool bvalid = dc < DIN;
    for (int m0 = 0; m0 < LL; m0 += 16) {
        float4 av = *(const float4*)&A[(size_t)(l0 + li) * LL + m0 + lq * 4];
        float4 bv = make_float4(0, 0, 0, 0);
        if (bvalid) bv = *(const float4*)&B[(size_t)(m0 + mm) * DIN + dc];
        __syncthreads();
        int lq4 = lq * 4;
        A_s[lq4 + 0][li] = av.x; A_s[lq4 + 1][li] = av.y; A_s[lq4 + 2][li] = av.z; A_s[lq4 + 3][li] = av.w;
        *(float4*)&B_s[mm][dq * 4] = bv;
        __syncthreads();
#pragma unroll
        for (int kk = 0; kk < 16; kk++) {
            float4 a = *(const float4*)&A_s[kk][ty * 4];
            float4 b = *(const float4*)&B_s[kk][tx * 4];
            float aa[4] = {a.x, a.y, a.z, a.w};
            float bb[4] = {b.x, b.y, b.z, b.w};
#pragma unroll
            for (int u = 0; u < 4; u++)
#pragma unroll
                for (int v = 0; v < 4; v++) acc[u][v] += aa[u] * bb[v];
        }
    }
#pragma unroll
    for (int u = 0; u < 4; u++) {
        int row = l0 + ty * 4 + u;
        int col = d0 + tx * 4;
        if (col < DIN) {
            float4 v = make_float4(acc[u][0], acc[u][1], acc[u][2], acc[u][3]);
            *(float4*)&agg[((size_t)n * LL + row) * DIN + col] = v;
        }
    }
}

// ---------------- fold (overlap-add gather) + divide by cnt -> zi -----------
__global__ void k_fold(const float* __restrict__ agg, float* __restrict__ zi) {
    int p = blockIdx.x * 256 + threadIdx.x;   // (n,ci,y,x)
    int x = p & 255, y = (p >> 8) & 255, ci = (p >> 16) & 15, n = p >> 20;
    int yp = y + 1, xp = x + 1;
    int lh1 = yp >> 2; if (lh1 > 63) lh1 = 63;
    int lh0 = (yp >= 3) ? ((yp - 3) >> 2) : 0;
    int lw1 = xp >> 2; if (lw1 > 63) lw1 = 63;
    int lw0 = (xp >= 3) ? ((xp - 3) >> 2) : 0;
    const float* an = agg + (size_t)n * LL * DIN;
    float sum = 0.f;
    for (int lh = lh0; lh <= lh1; lh++) {
        int dy = yp - 4 * lh;
        for (int lw = lw0; lw <= lw1; lw++) {
            int dx = xp - 4 * lw;
            sum += an[(size_t)(lh * 64 + lw) * DIN + ci * 49 + dy * 7 + dx];
        }
    }
    float cnt = (float)((lh1 - lh0 + 1) * (lw1 - lw0 + 1));
    zi[p] = sum / cnt;
}

// ---------------- final: out = b + zi @ W_w^T + W_b -------------------------
__global__ void k_final(const float* __restrict__ zi, const float* __restrict__ b,
                        const float* __restrict__ W_w, const float* __restrict__ W_b,
                        float* __restrict__ out) {
    __shared__ float w[16 * 64];   // [ci][co]
    int tid = threadIdx.x;
    for (int i = tid; i < 16 * 64; i += 256) {
        int ci = i >> 6; int co = i & 63;
        w[i] = W_w[co * 16 + ci];
    }
    __syncthreads();
    int p = blockIdx.x * 256 + tid;   // n*65536 + yx
    int n = p >> 16, yx = p & 65535;
    float acc[64];
#pragma unroll
    for (int co = 0; co < 64; co++) acc[co] = 0.f;
    const float* zn = zi + (size_t)n * 16 * 65536;
#pragma unroll
    for (int ci = 0; ci < 16; ci++) {
        float v = zn[ci * 65536 + yx];
#pragma unroll
        for (int co = 0; co < 64; co++) acc[co] += v * w[ci * 64 + co];
    }
    const float* bn = b + (size_t)n * 64 * 65536;
    float* on = out + (size_t)n * 64 * 65536;
#pragma unroll
    for (int co = 0; co < 64; co++) on[co * 65536 + yx] = bn[co * 65536 + yx] + acc[co] + W_b[co];
}

extern "C" void kernel_launch(void* const* d_in, const int* in_sizes, int n_in,
                              void* d_out, int out_size, void* d_ws, size_t ws_size,
                              hipStream_t stream) {
    const float* b     = (const float*)d_in[0];
    const float* g_w   = (const float*)d_in[1];
    const float* g_b   = (const float*)d_in[2];
    const float* th_w  = (const float*)d_in[3];
    const float* th_b  = (const float*)d_in[4];
    const float* W_w   = (const float*)d_in[5];
    const float* W_b   = (const float*)d_in[6];
    const float* fc1_w = (const float*)d_in[7];
    const float* fc1_b = (const float*)d_in[8];
    const float* fc2_w = (const float*)d_in[9];
    const float* fc2_b = (const float*)d_in[10];
    const float* thr_w = (const float*)d_in[11];
    const float* thr_b = (const float*)d_in[12];
    // d_in[13], d_in[14] (bias conv) unused: constant along softmax axis -> cancels.
    float* out = (float*)d_out;

    float* ws = (float*)d_ws;
    size_t off = 0;
    float* b1    = ws + off; off += (size_t)NB * CI * HH * WWD;  // 2,097,152
    float* b2    = ws + off; off += (size_t)NB * CI * HH * WWD;  // 2,097,152
    float* P     = ws + off; off += (size_t)NB * LL * DIN;       // 6,422,528
    float* pi    = ws + off; off += (size_t)NB * LL * DIN;       // 6,422,528
    float* wif   = ws + off; off += (size_t)NB * LL * DOUT;      // 1,605,632
    float* xif   = ws + off; off += (size_t)NB * LL * DOUT;      // 1,605,632
    float* thr   = ws + off; off += (size_t)NB * LL;             // 8,192
    float* rowM  = ws + off; off += (size_t)NB * LL;
    float* rowD  = ws + off; off += (size_t)NB * LL;
    float* score = ws + off; off += (size_t)NB * LL * LL;        // 33,554,432
    float* agg = P;    // P dead after k_fcgemm
    float* zi  = b1;   // b1 dead after k_patches

    k_conv<<<dim3(NB * 256), 256, 0, stream>>>(b, g_w, g_b, th_w, th_b, b1, b2);
    k_thr<<<dim3(32), 256, 0, stream>>>(b, thr_w, thr_b, thr);
    k_patches<<<dim3(25088), 256, 0, stream>>>(b1, b2, P, pi);
    k_fcgemm<<<dim3(128, 4), 256, 0, stream>>>(P, fc1_w, fc1_b, fc2_w, fc2_b, wif, xif);
    k_score<<<dim3(64, 64, NB), 256, 0, stream>>>(wif, xif, score);
    k_rowstats<<<dim3(NB * LL), 256, 0, stream>>>(score, thr, rowM, rowD);
    k_wxform<<<dim3(32768), 256, 0, stream>>>((float4*)score, thr, rowM, rowD);
    k_agg<<<dim3(64, 13, NB), 256, 0, stream>>>(score, pi, agg);
    k_fold<<<dim3(8192), 256, 0, stream>>>(agg, zi);
    k_final<<<dim3(512), 256, 0, stream>>>(zi, b, W_w, W_b, out);
}

// Round 2
// 824.819 us; speedup vs baseline: 2.1844x; 2.1844x over previous
//
#include <hip/hip_runtime.h>
#include <math.h>

#define CIN  64
#define CI   16
#define HH   256
#define WWD  256
#define KS   7
#define STR  4
#define LH   64
#define LWD  64
#define LL   4096
#define DIN  784
#define DINP 896     // padded to multiple of 128
#define DOUT 196
#define DOUTP 256    // padded K for score GEMM
#define NB   2

typedef __attribute__((ext_vector_type(8))) short bf16x8;
typedef __attribute__((ext_vector_type(4))) float f32x4;

__device__ __forceinline__ unsigned short f2bf(float x) {
    unsigned int u = __float_as_uint(x);
    unsigned int r = (u + 0x7FFFu + ((u >> 16) & 1u)) >> 16;
    return (unsigned short)r;
}
__device__ __forceinline__ float bf2f(unsigned short h) {
    return __uint_as_float(((unsigned int)h) << 16);
}

__device__ __forceinline__ void stage16(const void* g, void* l) {
#if defined(__has_builtin)
#if __has_builtin(__builtin_amdgcn_global_load_lds)
    __builtin_amdgcn_global_load_lds(
        (const __attribute__((address_space(1))) unsigned int*)g,
        (__attribute__((address_space(3))) unsigned int*)l, 16, 0, 0);
    return;
#endif
#endif
    *(float4*)l = *(const float4*)g;
}

// ---------------- conv3x3 (g) + conv1x1 (theta), 64ch -> 16ch, pad 1 / 0 ----
__global__ void k_conv(const float* __restrict__ b,
                       const float* __restrict__ g_w, const float* __restrict__ g_b,
                       const float* __restrict__ th_w, const float* __restrict__ th_b,
                       float* __restrict__ b1, float* __restrict__ b2) {
    __shared__ float wg[64 * 9 * 16];  // [ci][t][co]
    __shared__ float wt[64 * 16];      // [ci][co]
    int tid = threadIdx.x;
    for (int i = tid; i < 64 * 9 * 16; i += 256) {
        int co = i & 15; int rest = i >> 4; int t = rest % 9; int ci = rest / 9;
        wg[i] = g_w[(co * 64 + ci) * 9 + t];
    }
    for (int i = tid; i < 64 * 16; i += 256) {
        int co = i & 15; int ci = i >> 4;
        wt[i] = th_w[co * 64 + ci];
    }
    __syncthreads();
    int n = blockIdx.x >> 8;
    int p = ((blockIdx.x & 255) << 8) + tid;
    int y = p >> 8, x = p & 255;
    float acc1[16], acc2[16];
#pragma unroll
    for (int co = 0; co < 16; co++) { acc1[co] = g_b[co]; acc2[co] = th_b[co]; }
    const float* bn = b + (size_t)n * 64 * 65536;
    for (int ci = 0; ci < 64; ci++) {
        const float* bc = bn + ci * 65536;
#pragma unroll
        for (int dy = 0; dy < 3; dy++) {
            int yy = y + dy - 1;
            if (yy < 0 || yy > 255) continue;
#pragma unroll
            for (int dx = 0; dx < 3; dx++) {
                int xx = x + dx - 1;
                if (xx < 0 || xx > 255) continue;
                float v = bc[yy * 256 + xx];
                int t = dy * 3 + dx;
#pragma unroll
                for (int co = 0; co < 16; co++) acc1[co] += v * wg[(ci * 9 + t) * 16 + co];
                if (dy == 1 && dx == 1) {
#pragma unroll
                    for (int co = 0; co < 16; co++) acc2[co] += v * wt[ci * 16 + co];
                }
            }
        }
    }
    float* o1 = b1 + (size_t)n * 16 * 65536;
    float* o2 = b2 + (size_t)n * 16 * 65536;
#pragma unroll
    for (int co = 0; co < 16; co++) { o1[co * 65536 + p] = acc1[co]; o2[co * 65536 + p] = acc2[co]; }
}

// ---------------- thr: 7x7 stride-4 conv of padded b, 1 out channel ---------
__global__ void k_thr(const float* __restrict__ b, const float* __restrict__ thr_w,
                      const float* __restrict__ thr_b, float* __restrict__ thr) {
    __shared__ float w[64 * 49];
    int tid = threadIdx.x;
    for (int i = tid; i < 64 * 49; i += 256) w[i] = thr_w[i];
    __syncthreads();
    int g = blockIdx.x * 256 + tid;
    int n = g >> 12; int l = g & 4095;
    int lh = l >> 6, lw = l & 63;
    float acc = thr_b[0];
    const float* bn = b + (size_t)n * 64 * 65536;
    for (int ci = 0; ci < 64; ci++) {
        const float* bc = bn + ci * 65536;
        for (int dy = 0; dy < 7; dy++) {
            int y = lh * 4 + dy - 1;
            if (y < 0 || y > 255) continue;
            for (int dx = 0; dx < 7; dx++) {
                int x = lw * 4 + dx - 1;
                if (x < 0 || x > 255) continue;
                acc += bc[y * 256 + x] * w[ci * 49 + dy * 7 + dx];
            }
        }
    }
    thr[g] = acc;
}

// ---------------- patch extraction of b1 -> P (fp32, for fcgemm) ------------
__global__ void k_patches(const float* __restrict__ b1, float* __restrict__ P) {
    size_t e = (size_t)blockIdx.x * 256 + threadIdx.x;
    size_t total = (size_t)NB * LL * DIN;
    if (e >= total) return;
    int d = (int)(e % DIN); size_t r = e / DIN;
    int l = (int)(r & 4095); int n = (int)(r >> 12);
    int ci = d / 49; int t = d % 49; int dy = t / 7; int dx = t % 7;
    int lh = l >> 6, lw = l & 63;
    int y = lh * 4 + dy - 1, x = lw * 4 + dx - 1;
    float v1 = 0.f;
    if (y >= 0 && y < 256 && x >= 0 && x < 256)
        v1 = b1[((size_t)(n * 16 + ci) * 256 + y) * 256 + x];
    P[e] = v1;
}

// ---------------- patch extraction of b2 -> piT bf16 [n][d][l], d padded ----
__global__ void k_patchesT(const float* __restrict__ b2, unsigned short* __restrict__ piT) {
    size_t e = (size_t)blockIdx.x * 256 + threadIdx.x;   // over n*DINP*LL
    int l = (int)(e & 4095);
    int d = (int)((e >> 12) % DINP);
    int n = (int)(e / ((size_t)DINP * LL));
    float v = 0.f;
    if (d < DIN) {
        int ci = d / 49; int t = d % 49; int dy = t / 7; int dx = t % 7;
        int y = (l >> 6) * 4 + dy - 1, x = (l & 63) * 4 + dx - 1;
        if (y >= 0 && y < 256 && x >= 0 && x < 256)
            v = b2[((size_t)(n * 16 + ci) * 256 + y) * 256 + x];
    }
    piT[e] = f2bf(v);
}

// ---------------- FC GEMM (fp32): wifb/xifb = relu(P@fc^T+b) as bf16 padded -
__global__ void k_fcgemm(const float* __restrict__ P,
                         const float* __restrict__ fc1_w, const float* __restrict__ fc1_b,
                         const float* __restrict__ fc2_w, const float* __restrict__ fc2_b,
                         unsigned short* __restrict__ wifb, unsigned short* __restrict__ xifb) {
    __shared__ float A_s[16][64], W1_s[16][64], W2_s[16][64];
    int tid = threadIdx.x;
    int tx = tid & 15, ty = tid >> 4;
    int li = tid >> 2, lq = tid & 3;
    int i0 = blockIdx.x * 64, o0 = blockIdx.y * 64;
    float acc1[4][4] = {{0.f}}, acc2[4][4] = {{0.f}};
    bool wvalid = (o0 + li) < DOUT;
    const float* aptr = P + (size_t)(i0 + li) * DIN + lq * 4;
    const float* w1p = fc1_w + (size_t)(o0 + li) * DIN + lq * 4;
    const float* w2p = fc2_w + (size_t)(o0 + li) * DIN + lq * 4;
    for (int k0 = 0; k0 < DIN; k0 += 16) {
        float4 av = *(const float4*)(aptr + k0);
        float4 w1v = make_float4(0, 0, 0, 0), w2v = make_float4(0, 0, 0, 0);
        if (wvalid) { w1v = *(const float4*)(w1p + k0); w2v = *(const float4*)(w2p + k0); }
        __syncthreads();
        int lq4 = lq * 4;
        A_s[lq4 + 0][li] = av.x; A_s[lq4 + 1][li] = av.y; A_s[lq4 + 2][li] = av.z; A_s[lq4 + 3][li] = av.w;
        W1_s[lq4 + 0][li] = w1v.x; W1_s[lq4 + 1][li] = w1v.y; W1_s[lq4 + 2][li] = w1v.z; W1_s[lq4 + 3][li] = w1v.w;
        W2_s[lq4 + 0][li] = w2v.x; W2_s[lq4 + 1][li] = w2v.y; W2_s[lq4 + 2][li] = w2v.z; W2_s[lq4 + 3][li] = w2v.w;
        __syncthreads();
#pragma unroll
        for (int kk = 0; kk < 16; kk++) {
            float4 a = *(const float4*)&A_s[kk][ty * 4];
            float4 w1 = *(const float4*)&W1_s[kk][tx * 4];
            float4 w2 = *(const float4*)&W2_s[kk][tx * 4];
            float aa[4] = {a.x, a.y, a.z, a.w};
            float b1a[4] = {w1.x, w1.y, w1.z, w1.w};
            float b2a[4] = {w2.x, w2.y, w2.z, w2.w};
#pragma unroll
            for (int u = 0; u < 4; u++)
#pragma unroll
                for (int v = 0; v < 4; v++) { acc1[u][v] += aa[u] * b1a[v]; acc2[u][v] += aa[u] * b2a[v]; }
        }
    }
#pragma unroll
    for (int u = 0; u < 4; u++) {
        int row = i0 + ty * 4 + u;
#pragma unroll
        for (int v = 0; v < 4; v++) {
            int col = o0 + tx * 4 + v;
            float v1 = 0.f, v2 = 0.f;
            if (col < DOUT) {
                v1 = fmaxf(acc1[u][v] + fc1_b[col], 0.f);
                v2 = fmaxf(acc2[u][v] + fc2_b[col], 0.f);
            }
            wifb[(size_t)row * DOUTP + col] = f2bf(v1);
            xifb[(size_t)row * DOUTP + col] = f2bf(v2);
        }
    }
}

// ---------------- MFMA GEMM (NT): C[MxN] = A[MxK] * Bt[NxK]^T ---------------
// A, Bt bf16 row-major (K contiguous). 128x128 block tile, BK=64, 4 waves 2x2.
// XOR-swizzled LDS (slot ^= row&7) to break bank conflicts; global_load_lds x16.
template<bool STORE_BF16>
__global__ __launch_bounds__(256) void k_gemm_nt(
        const unsigned short* __restrict__ A, const unsigned short* __restrict__ Bt,
        void* __restrict__ C, int lda, int ldb, int ldc, int K,
        size_t sA, size_t sB, size_t sC) {
    __shared__ unsigned short lA[128 * 64];
    __shared__ unsigned short lB[128 * 64];
    int tid = threadIdx.x;
    int wave = tid >> 6, lane = tid & 63;
    int lr = lane & 15, lq = lane >> 4;
    int wm = (wave >> 1) * 64, wn = (wave & 1) * 64;
    int i0 = blockIdx.x * 128, j0 = blockIdx.y * 128;
    const unsigned short* Ab = A + (size_t)blockIdx.z * sA + (size_t)i0 * lda;
    const unsigned short* Bb = Bt + (size_t)blockIdx.z * sB + (size_t)j0 * ldb;
    f32x4 acc[4][4] = {};
    for (int k0 = 0; k0 < K; k0 += 64) {
        __syncthreads();
#pragma unroll
        for (int it = 0; it < 4; it++) {
            int c = it * 256 + tid;
            int row = c >> 3, slot = c & 7;
            int col8 = slot ^ (row & 7);
            stage16(Ab + (size_t)row * lda + k0 + col8 * 8, &lA[c * 8]);
        }
#pragma unroll
        for (int it = 0; it < 4; it++) {
            int c = it * 256 + tid;
            int row = c >> 3, slot = c & 7;
            int col8 = slot ^ (row & 7);
            stage16(Bb + (size_t)row * ldb + k0 + col8 * 8, &lB[c * 8]);
        }
        __syncthreads();
#pragma unroll
        for (int ks = 0; ks < 2; ks++) {
            bf16x8 af[4], bfr[4];
#pragma unroll
            for (int t = 0; t < 4; t++) {
                int row = wm + t * 16 + lr;
                int slot = ks * 4 + lq;
                af[t] = *(const bf16x8*)&lA[row * 64 + (slot ^ (row & 7)) * 8];
            }
#pragma unroll
            for (int t = 0; t < 4; t++) {
                int row = wn + t * 16 + lr;
                int slot = ks * 4 + lq;
                bfr[t] = *(const bf16x8*)&lB[row * 64 + (slot ^ (row & 7)) * 8];
            }
#pragma unroll
            for (int mi = 0; mi < 4; mi++)
#pragma unroll
                for (int nj = 0; nj < 4; nj++)
                    acc[mi][nj] = __builtin_amdgcn_mfma_f32_16x16x32_bf16(
                        af[mi], bfr[nj], acc[mi][nj], 0, 0, 0);
        }
    }
    if (STORE_BF16) {
        unsigned short* Cb = (unsigned short*)C + (size_t)blockIdx.z * sC;
#pragma unroll
        for (int mi = 0; mi < 4; mi++)
#pragma unroll
            for (int r = 0; r < 4; r++) {
                int row = i0 + wm + mi * 16 + lq * 4 + r;
#pragma unroll
                for (int nj = 0; nj < 4; nj++) {
                    int col = j0 + wn + nj * 16 + lr;
                    Cb[(size_t)row * ldc + col] = f2bf(acc[mi][nj][r]);
                }
            }
    } else {
        float* Cf = (float*)C + (size_t)blockIdx.z * sC;
#pragma unroll
        for (int mi = 0; mi < 4; mi++)
#pragma unroll
            for (int r = 0; r < 4; r++) {
                int row = i0 + wm + mi * 16 + lq * 4 + r;
#pragma unroll
                for (int nj = 0; nj < 4; nj++) {
                    int col = j0 + wn + nj * 16 + lr;
                    Cf[(size_t)row * ldc + col] = acc[mi][nj][r];
                }
            }
    }
}

// ---------------- per-row softmax stats over bf16 score ---------------------
__global__ void k_rowstats(const unsigned short* __restrict__ score, const float* __restrict__ thr,
                           float* __restrict__ rowM, float* __restrict__ rowD) {
    __shared__ float red[256], red2[256];
    int row = blockIdx.x;
    int tid = threadIdx.x;
    const uint4* s4 = (const uint4*)(score + (size_t)row * LL);
    float t = thr[row];
    float mx = 0.f;
    for (int c = tid; c < 512; c += 256) {
        uint4 u = s4[c];
        unsigned int w[4] = {u.x, u.y, u.z, u.w};
#pragma unroll
        for (int q = 0; q < 4; q++) {
            float v0 = __uint_as_float(w[q] << 16);
            float v1 = __uint_as_float(w[q] & 0xFFFF0000u);
            if (v0 >= t) mx = fmaxf(mx, v0);
            if (v1 >= t) mx = fmaxf(mx, v1);
        }
    }
    red[tid] = mx; __syncthreads();
    for (int st = 128; st > 0; st >>= 1) {
        if (tid < st) red[tid] = fmaxf(red[tid], red[tid + st]);
        __syncthreads();
    }
    float M = 10.f * fmaxf(red[0], 0.f);
    __syncthreads();
    float s2 = 0.f, n0 = 0.f;
    for (int c = tid; c < 512; c += 256) {
        uint4 u = s4[c];
        unsigned int w[4] = {u.x, u.y, u.z, u.w};
#pragma unroll
        for (int q = 0; q < 4; q++) {
            float v0 = __uint_as_float(w[q] << 16);
            float v1 = __uint_as_float(w[q] & 0xFFFF0000u);
            if (v0 >= t) s2 += __expf(10.f * v0 - M); else n0 += 1.f;
            if (v1 >= t) s2 += __expf(10.f * v1 - M); else n0 += 1.f;
        }
    }
    red[tid] = s2; red2[tid] = n0; __syncthreads();
    for (int st = 128; st > 0; st >>= 1) {
        if (tid < st) { red[tid] += red[tid + st]; red2[tid] += red2[tid + st]; }
        __syncthreads();
    }
    if (tid == 0) {
        float S2 = red[0], N0 = red2[0];
        float D = S2 + 1e-8f * (S2 + N0 * __expf(-M));
        rowM[row] = M;
        rowD[row] = 1.f / D;
    }
}

// ---------------- transform bf16 score -> bf16 attn in place ----------------
__global__ void k_wxform(unsigned short* __restrict__ s, const float* __restrict__ thr,
                         const float* __restrict__ rowM, const float* __restrict__ rowD) {
    size_t i = (size_t)blockIdx.x * 256 + threadIdx.x;   // 4,194,304 threads, 8 elems each
    int row = (int)(i >> 9);
    float t = thr[row], M = rowM[row], iD = rowD[row];
    uint4* p = (uint4*)s + i;
    uint4 u = *p;
    unsigned int w[4] = {u.x, u.y, u.z, u.w};
    unsigned int o[4];
#pragma unroll
    for (int q = 0; q < 4; q++) {
        float v0 = __uint_as_float(w[q] << 16);
        float v1 = __uint_as_float(w[q] & 0xFFFF0000u);
        float a0 = (v0 >= t) ? __expf(10.f * v0 - M) * iD : 0.f;
        float a1 = (v1 >= t) ? __expf(10.f * v1 - M) * iD : 0.f;
        o[q] = (unsigned int)f2bf(a0) | ((unsigned int)f2bf(a1) << 16);
    }
    *p = make_uint4(o[0], o[1], o[2], o[3]);
}

// ---------------- fold (overlap-add gather) + divide by cnt -> zi -----------
__global__ void k_fold(const float* __restrict__ agg, float* __restrict__ zi) {
    int p = blockIdx.x * 256 + threadIdx.x;
    int x = p & 255, y = (p >> 8) & 255, ci = (p >> 16) & 15, n = p >> 20;
    int yp = y + 1, xp = x + 1;
    int lh1 = yp >> 2; if (lh1 > 63) lh1 = 63;
    int lh0 = (yp >= 3) ? ((yp - 3) >> 2) : 0;
    int lw1 = xp >> 2; if (lw1 > 63) lw1 = 63;
    int lw0 = (xp >= 3) ? ((xp - 3) >> 2) : 0;
    const float* an = agg + (size_t)n * LL * DINP;
    float sum = 0.f;
    for (int lh = lh0; lh <= lh1; lh++) {
        int dy = yp - 4 * lh;
        for (int lw = lw0; lw <= lw1; lw++) {
            int dx = xp - 4 * lw;
            sum += an[(size_t)(lh * 64 + lw) * DINP + ci * 49 + dy * 7 + dx];
        }
    }
    float cnt = (float)((lh1 - lh0 + 1) * (lw1 - lw0 + 1));
    zi[p] = sum / cnt;
}

// ---------------- final: out = b + zi @ W_w^T + W_b -------------------------
__global__ void k_final(const float* __restrict__ zi, const float* __restrict__ b,
                        const float* __restrict__ W_w, const float* __restrict__ W_b,
                        float* __restrict__ out) {
    __shared__ float w[16 * 64];
    int tid = threadIdx.x;
    for (int i = tid; i < 16 * 64; i += 256) {
        int ci = i >> 6; int co = i & 63;
        w[i] = W_w[co * 16 + ci];
    }
    __syncthreads();
    int p = blockIdx.x * 256 + tid;
    int n = p >> 16, yx = p & 65535;
    float acc[64];
#pragma unroll
    for (int co = 0; co < 64; co++) acc[co] = 0.f;
    const float* zn = zi + (size_t)n * 16 * 65536;
#pragma unroll
    for (int ci = 0; ci < 16; ci++) {
        float v = zn[ci * 65536 + yx];
#pragma unroll
        for (int co = 0; co < 64; co++) acc[co] += v * w[ci * 64 + co];
    }
    const float* bn = b + (size_t)n * 64 * 65536;
    float* on = out + (size_t)n * 64 * 65536;
#pragma unroll
    for (int co = 0; co < 64; co++) on[co * 65536 + yx] = bn[co * 65536 + yx] + acc[co] + W_b[co];
}

extern "C" void kernel_launch(void* const* d_in, const int* in_sizes, int n_in,
                              void* d_out, int out_size, void* d_ws, size_t ws_size,
                              hipStream_t stream) {
    const float* b     = (const float*)d_in[0];
    const float* g_w   = (const float*)d_in[1];
    const float* g_b   = (const float*)d_in[2];
    const float* th_w  = (const float*)d_in[3];
    const float* th_b  = (const float*)d_in[4];
    const float* W_w   = (const float*)d_in[5];
    const float* W_b   = (const float*)d_in[6];
    const float* fc1_w = (const float*)d_in[7];
    const float* fc1_b = (const float*)d_in[8];
    const float* fc2_w = (const float*)d_in[9];
    const float* fc2_b = (const float*)d_in[10];
    const float* thr_w = (const float*)d_in[11];
    const float* thr_b = (const float*)d_in[12];
    // d_in[13], d_in[14] (bias conv): constant along softmax axis -> cancels.
    float* out = (float*)d_out;

    float* ws = (float*)d_ws;
    size_t off = 0;
    auto alloc = [&](size_t nf) { float* p = ws + off; off += (nf + 63) & ~(size_t)63; return p; };
    float* b1   = alloc((size_t)NB * CI * HH * WWD);          // 2,097,152 f
    float* b2   = alloc((size_t)NB * CI * HH * WWD);          // 2,097,152 f
    float* P    = alloc((size_t)NB * LL * DIN);               // 6,422,528 f
    float* agg  = alloc((size_t)NB * LL * DINP);              // 7,340,032 f
    unsigned short* piT  = (unsigned short*)alloc((size_t)NB * DINP * LL / 2);   // bf16
    unsigned short* wifb = (unsigned short*)alloc((size_t)NB * LL * DOUTP / 2);  // bf16
    unsigned short* xifb = (unsigned short*)alloc((size_t)NB * LL * DOUTP / 2);  // bf16
    float* thr  = alloc((size_t)NB * LL);
    float* rowM = alloc((size_t)NB * LL);
    float* rowD = alloc((size_t)NB * LL);
    unsigned short* score = (unsigned short*)alloc((size_t)NB * LL * LL / 2);    // bf16, becomes attn
    float* zi = b1;   // b1 dead after k_patches

    k_conv<<<dim3(NB * 256), 256, 0, stream>>>(b, g_w, g_b, th_w, th_b, b1, b2);
    k_thr<<<dim3(32), 256, 0, stream>>>(b, thr_w, thr_b, thr);
    k_patches<<<dim3(25088), 256, 0, stream>>>(b1, P);
    k_patchesT<<<dim3(28672), 256, 0, stream>>>(b2, piT);
    k_fcgemm<<<dim3(128, 4), 256, 0, stream>>>(P, fc1_w, fc1_b, fc2_w, fc2_b, wifb, xifb);
    // score[l][m] = wif[l].xif[m]  (bf16 out)
    k_gemm_nt<true><<<dim3(32, 32, NB), 256, 0, stream>>>(
        wifb, xifb, (void*)score, DOUTP, DOUTP, LL, DOUTP,
        (size_t)LL * DOUTP, (size_t)LL * DOUTP, (size_t)LL * LL);
    k_rowstats<<<dim3(NB * LL), 256, 0, stream>>>(score, thr, rowM, rowD);
    k_wxform<<<dim3(16384), 256, 0, stream>>>(score, thr, rowM, rowD);
    // agg[l][d] = sum_m attn[l][m] * piT[d][m]  (fp32 out)
    k_gemm_nt<false><<<dim3(32, DINP / 128, NB), 256, 0, stream>>>(
        score, piT, (void*)agg, LL, LL, DINP, LL,
        (size_t)LL * LL, (size_t)DINP * LL, (size_t)LL * DINP);
    k_fold<<<dim3(8192), 256, 0, stream>>>(agg, zi);
    k_final<<<dim3(512), 256, 0, stream>>>(zi, b, W_w, W_b, out);
}

// Round 3
// 625.723 us; speedup vs baseline: 2.8795x; 1.3182x over previous
//
#include <hip/hip_runtime.h>
#include <math.h>

#define CIN  64
#define CI   16
#define HH   256
#define WWD  256
#define KS   7
#define STR  4
#define LH   64
#define LWD  64
#define LL   4096
#define DIN  784
#define DINP 896     // padded to multiple of 128
#define DOUT 196
#define DOUTP 256    // padded K for score GEMM
#define NB   2

typedef __attribute__((ext_vector_type(8))) short bf16x8;
typedef __attribute__((ext_vector_type(4))) float f32x4;

__device__ __forceinline__ unsigned short f2bf(float x) {
    unsigned int u = __float_as_uint(x);
    unsigned int r = (u + 0x7FFFu + ((u >> 16) & 1u)) >> 16;
    return (unsigned short)r;
}
__device__ __forceinline__ float bf2f(unsigned short h) {
    return __uint_as_float(((unsigned int)h) << 16);
}

__device__ __forceinline__ void stage16(const void* g, void* l) {
#if defined(__has_builtin)
#if __has_builtin(__builtin_amdgcn_global_load_lds)
    __builtin_amdgcn_global_load_lds(
        (const __attribute__((address_space(1))) unsigned int*)g,
        (__attribute__((address_space(3))) unsigned int*)l, 16, 0, 0);
    return;
#endif
#endif
    *(float4*)l = *(const float4*)g;
}

// ---------------- conv3x3 (g) + conv1x1 (theta), 64ch -> 16ch, pad 1 / 0 ----
__global__ void k_conv(const float* __restrict__ b,
                       const float* __restrict__ g_w, const float* __restrict__ g_b,
                       const float* __restrict__ th_w, const float* __restrict__ th_b,
                       float* __restrict__ b1, float* __restrict__ b2) {
    __shared__ float wg[64 * 9 * 16];  // [ci][t][co]
    __shared__ float wt[64 * 16];      // [ci][co]
    int tid = threadIdx.x;
    for (int i = tid; i < 64 * 9 * 16; i += 256) {
        int co = i & 15; int rest = i >> 4; int t = rest % 9; int ci = rest / 9;
        wg[i] = g_w[(co * 64 + ci) * 9 + t];
    }
    for (int i = tid; i < 64 * 16; i += 256) {
        int co = i & 15; int ci = i >> 4;
        wt[i] = th_w[co * 64 + ci];
    }
    __syncthreads();
    int n = blockIdx.x >> 8;
    int p = ((blockIdx.x & 255) << 8) + tid;
    int y = p >> 8, x = p & 255;
    float acc1[16], acc2[16];
#pragma unroll
    for (int co = 0; co < 16; co++) { acc1[co] = g_b[co]; acc2[co] = th_b[co]; }
    const float* bn = b + (size_t)n * 64 * 65536;
    for (int ci = 0; ci < 64; ci++) {
        const float* bc = bn + ci * 65536;
#pragma unroll
        for (int dy = 0; dy < 3; dy++) {
            int yy = y + dy - 1;
            if (yy < 0 || yy > 255) continue;
#pragma unroll
            for (int dx = 0; dx < 3; dx++) {
                int xx = x + dx - 1;
                if (xx < 0 || xx > 255) continue;
                float v = bc[yy * 256 + xx];
                int t = dy * 3 + dx;
#pragma unroll
                for (int co = 0; co < 16; co++) acc1[co] += v * wg[(ci * 9 + t) * 16 + co];
                if (dy == 1 && dx == 1) {
#pragma unroll
                    for (int co = 0; co < 16; co++) acc2[co] += v * wt[ci * 16 + co];
                }
            }
        }
    }
    float* o1 = b1 + (size_t)n * 16 * 65536;
    float* o2 = b2 + (size_t)n * 16 * 65536;
#pragma unroll
    for (int co = 0; co < 16; co++) { o1[co * 65536 + p] = acc1[co]; o2[co * 65536 + p] = acc2[co]; }
}

// ---------------- thr: 7x7 stride-4 conv, one WAVE per output, lane = ci ----
__global__ __launch_bounds__(256) void k_thr(
        const float* __restrict__ b, const float* __restrict__ thr_w,
        const float* __restrict__ thr_b, float* __restrict__ thr) {
    __shared__ float w[64 * 49];
    int tid = threadIdx.x;
    for (int i = tid; i < 64 * 49; i += 256) w[i] = thr_w[i];
    __syncthreads();
    int wid = (blockIdx.x << 2) + (tid >> 6);   // 0..8191 output index
    int lane = tid & 63;
    int n = wid >> 12, l = wid & 4095;
    int lh = (l >> 6), lw = l & 63;
    const float* bc = b + (size_t)(n * 64 + lane) * 65536;
    const float* wl = w + lane * 49;
    float acc = 0.f;
#pragma unroll
    for (int dy = 0; dy < 7; dy++) {
        int y = lh * 4 + dy - 1;
        if (y < 0 || y > 255) continue;        // wave-uniform branch
        const float* br = bc + y * 256;
#pragma unroll
        for (int dx = 0; dx < 7; dx++) {
            int x = lw * 4 + dx - 1;
            if (x < 0 || x > 255) continue;    // wave-uniform branch
            acc += br[x] * wl[dy * 7 + dx];
        }
    }
#pragma unroll
    for (int off = 32; off > 0; off >>= 1) acc += __shfl_down(acc, off, 64);
    if (lane == 0) thr[wid] = acc + thr_b[0];
}

// ---------------- patch extraction of b1 -> P (fp32, for fcgemm) ------------
__global__ void k_patches(const float* __restrict__ b1, float* __restrict__ P) {
    size_t e = (size_t)blockIdx.x * 256 + threadIdx.x;
    size_t total = (size_t)NB * LL * DIN;
    if (e >= total) return;
    int d = (int)(e % DIN); size_t r = e / DIN;
    int l = (int)(r & 4095); int n = (int)(r >> 12);
    int ci = d / 49; int t = d % 49; int dy = t / 7; int dx = t % 7;
    int lh = l >> 6, lw = l & 63;
    int y = lh * 4 + dy - 1, x = lw * 4 + dx - 1;
    float v1 = 0.f;
    if (y >= 0 && y < 256 && x >= 0 && x < 256)
        v1 = b1[((size_t)(n * 16 + ci) * 256 + y) * 256 + x];
    P[e] = v1;
}

// ---------------- patch extraction of b2 -> piT bf16 [n][d][l], d padded ----
__global__ void k_patchesT(const float* __restrict__ b2, unsigned short* __restrict__ piT) {
    size_t e = (size_t)blockIdx.x * 256 + threadIdx.x;   // over n*DINP*LL
    int l = (int)(e & 4095);
    int d = (int)((e >> 12) % DINP);
    int n = (int)(e / ((size_t)DINP * LL));
    float v = 0.f;
    if (d < DIN) {
        int ci = d / 49; int t = d % 49; int dy = t / 7; int dx = t % 7;
        int y = (l >> 6) * 4 + dy - 1, x = (l & 63) * 4 + dx - 1;
        if (y >= 0 && y < 256 && x >= 0 && x < 256)
            v = b2[((size_t)(n * 16 + ci) * 256 + y) * 256 + x];
    }
    piT[e] = f2bf(v);
}

// ---------------- FC GEMM (fp32): wifb/xifb = relu(P@fc^T+b) as bf16 padded -
__global__ void k_fcgemm(const float* __restrict__ P,
                         const float* __restrict__ fc1_w, const float* __restrict__ fc1_b,
                         const float* __restrict__ fc2_w, const float* __restrict__ fc2_b,
                         unsigned short* __restrict__ wifb, unsigned short* __restrict__ xifb) {
    __shared__ float A_s[16][64], W1_s[16][64], W2_s[16][64];
    int tid = threadIdx.x;
    int tx = tid & 15, ty = tid >> 4;
    int li = tid >> 2, lq = tid & 3;
    int i0 = blockIdx.x * 64, o0 = blockIdx.y * 64;
    float acc1[4][4] = {{0.f}}, acc2[4][4] = {{0.f}};
    bool wvalid = (o0 + li) < DOUT;
    const float* aptr = P + (size_t)(i0 + li) * DIN + lq * 4;
    const float* w1p = fc1_w + (size_t)(o0 + li) * DIN + lq * 4;
    const float* w2p = fc2_w + (size_t)(o0 + li) * DIN + lq * 4;
    for (int k0 = 0; k0 < DIN; k0 += 16) {
        float4 av = *(const float4*)(aptr + k0);
        float4 w1v = make_float4(0, 0, 0, 0), w2v = make_float4(0, 0, 0, 0);
        if (wvalid) { w1v = *(const float4*)(w1p + k0); w2v = *(const float4*)(w2p + k0); }
        __syncthreads();
        int lq4 = lq * 4;
        A_s[lq4 + 0][li] = av.x; A_s[lq4 + 1][li] = av.y; A_s[lq4 + 2][li] = av.z; A_s[lq4 + 3][li] = av.w;
        W1_s[lq4 + 0][li] = w1v.x; W1_s[lq4 + 1][li] = w1v.y; W1_s[lq4 + 2][li] = w1v.z; W1_s[lq4 + 3][li] = w1v.w;
        W2_s[lq4 + 0][li] = w2v.x; W2_s[lq4 + 1][li] = w2v.y; W2_s[lq4 + 2][li] = w2v.z; W2_s[lq4 + 3][li] = w2v.w;
        __syncthreads();
#pragma unroll
        for (int kk = 0; kk < 16; kk++) {
            float4 a = *(const float4*)&A_s[kk][ty * 4];
            float4 w1 = *(const float4*)&W1_s[kk][tx * 4];
            float4 w2 = *(const float4*)&W2_s[kk][tx * 4];
            float aa[4] = {a.x, a.y, a.z, a.w};
            float b1a[4] = {w1.x, w1.y, w1.z, w1.w};
            float b2a[4] = {w2.x, w2.y, w2.z, w2.w};
#pragma unroll
            for (int u = 0; u < 4; u++)
#pragma unroll
                for (int v = 0; v < 4; v++) { acc1[u][v] += aa[u] * b1a[v]; acc2[u][v] += aa[u] * b2a[v]; }
        }
    }
#pragma unroll
    for (int u = 0; u < 4; u++) {
        int row = i0 + ty * 4 + u;
#pragma unroll
        for (int v = 0; v < 4; v++) {
            int col = o0 + tx * 4 + v;
            float v1 = 0.f, v2 = 0.f;
            if (col < DOUT) {
                v1 = fmaxf(acc1[u][v] + fc1_b[col], 0.f);
                v2 = fmaxf(acc2[u][v] + fc2_b[col], 0.f);
            }
            wifb[(size_t)row * DOUTP + col] = f2bf(v1);
            xifb[(size_t)row * DOUTP + col] = f2bf(v2);
        }
    }
}

// ---------------- MFMA GEMM (NT): C[MxN] = A[MxK] * Bt[NxK]^T ---------------
template<bool STORE_BF16>
__global__ __launch_bounds__(256) void k_gemm_nt(
        const unsigned short* __restrict__ A, const unsigned short* __restrict__ Bt,
        void* __restrict__ C, int lda, int ldb, int ldc, int K,
        size_t sA, size_t sB, size_t sC) {
    __shared__ unsigned short lA[128 * 64];
    __shared__ unsigned short lB[128 * 64];
    int tid = threadIdx.x;
    int wave = tid >> 6, lane = tid & 63;
    int lr = lane & 15, lq = lane >> 4;
    int wm = (wave >> 1) * 64, wn = (wave & 1) * 64;
    int i0 = blockIdx.x * 128, j0 = blockIdx.y * 128;
    const unsigned short* Ab = A + (size_t)blockIdx.z * sA + (size_t)i0 * lda;
    const unsigned short* Bb = Bt + (size_t)blockIdx.z * sB + (size_t)j0 * ldb;
    f32x4 acc[4][4] = {};
    for (int k0 = 0; k0 < K; k0 += 64) {
        __syncthreads();
#pragma unroll
        for (int it = 0; it < 4; it++) {
            int c = it * 256 + tid;
            int row = c >> 3, slot = c & 7;
            int col8 = slot ^ (row & 7);
            stage16(Ab + (size_t)row * lda + k0 + col8 * 8, &lA[c * 8]);
        }
#pragma unroll
        for (int it = 0; it < 4; it++) {
            int c = it * 256 + tid;
            int row = c >> 3, slot = c & 7;
            int col8 = slot ^ (row & 7);
            stage16(Bb + (size_t)row * ldb + k0 + col8 * 8, &lB[c * 8]);
        }
        __syncthreads();
#pragma unroll
        for (int ks = 0; ks < 2; ks++) {
            bf16x8 af[4], bfr[4];
#pragma unroll
            for (int t = 0; t < 4; t++) {
                int row = wm + t * 16 + lr;
                int slot = ks * 4 + lq;
                af[t] = *(const bf16x8*)&lA[row * 64 + (slot ^ (row & 7)) * 8];
            }
#pragma unroll
            for (int t = 0; t < 4; t++) {
                int row = wn + t * 16 + lr;
                int slot = ks * 4 + lq;
                bfr[t] = *(const bf16x8*)&lB[row * 64 + (slot ^ (row & 7)) * 8];
            }
#pragma unroll
            for (int mi = 0; mi < 4; mi++)
#pragma unroll
                for (int nj = 0; nj < 4; nj++)
                    acc[mi][nj] = __builtin_amdgcn_mfma_f32_16x16x32_bf16(
                        af[mi], bfr[nj], acc[mi][nj], 0, 0, 0);
        }
    }
    if (STORE_BF16) {
        unsigned short* Cb = (unsigned short*)C + (size_t)blockIdx.z * sC;
#pragma unroll
        for (int mi = 0; mi < 4; mi++)
#pragma unroll
            for (int r = 0; r < 4; r++) {
                int row = i0 + wm + mi * 16 + lq * 4 + r;
#pragma unroll
                for (int nj = 0; nj < 4; nj++) {
                    int col = j0 + wn + nj * 16 + lr;
                    Cb[(size_t)row * ldc + col] = f2bf(acc[mi][nj][r]);
                }
            }
    } else {
        float* Cf = (float*)C + (size_t)blockIdx.z * sC;
#pragma unroll
        for (int mi = 0; mi < 4; mi++)
#pragma unroll
            for (int r = 0; r < 4; r++) {
                int row = i0 + wm + mi * 16 + lq * 4 + r;
#pragma unroll
                for (int nj = 0; nj < 4; nj++) {
                    int col = j0 + wn + nj * 16 + lr;
                    Cf[(size_t)row * ldc + col] = acc[mi][nj][r];
                }
            }
    }
}

// ---------------- per-row softmax stats over bf16 score ---------------------
__global__ void k_rowstats(const unsigned short* __restrict__ score, const float* __restrict__ thr,
                           float* __restrict__ rowM, float* __restrict__ rowD) {
    __shared__ float red[256], red2[256];
    int row = blockIdx.x;
    int tid = threadIdx.x;
    const uint4* s4 = (const uint4*)(score + (size_t)row * LL);
    float t = thr[row];
    float mx = 0.f;
    for (int c = tid; c < 512; c += 256) {
        uint4 u = s4[c];
        unsigned int w[4] = {u.x, u.y, u.z, u.w};
#pragma unroll
        for (int q = 0; q < 4; q++) {
            float v0 = __uint_as_float(w[q] << 16);
            float v1 = __uint_as_float(w[q] & 0xFFFF0000u);
            if (v0 >= t) mx = fmaxf(mx, v0);
            if (v1 >= t) mx = fmaxf(mx, v1);
        }
    }
    red[tid] = mx; __syncthreads();
    for (int st = 128; st > 0; st >>= 1) {
        if (tid < st) red[tid] = fmaxf(red[tid], red[tid + st]);
        __syncthreads();
    }
    float M = 10.f * fmaxf(red[0], 0.f);
    __syncthreads();
    float s2 = 0.f, n0 = 0.f;
    for (int c = tid; c < 512; c += 256) {
        uint4 u = s4[c];
        unsigned int w[4] = {u.x, u.y, u.z, u.w};
#pragma unroll
        for (int q = 0; q < 4; q++) {
            float v0 = __uint_as_float(w[q] << 16);
            float v1 = __uint_as_float(w[q] & 0xFFFF0000u);
            if (v0 >= t) s2 += __expf(10.f * v0 - M); else n0 += 1.f;
            if (v1 >= t) s2 += __expf(10.f * v1 - M); else n0 += 1.f;
        }
    }
    red[tid] = s2; red2[tid] = n0; __syncthreads();
    for (int st = 128; st > 0; st >>= 1) {
        if (tid < st) { red[tid] += red[tid + st]; red2[tid] += red2[tid + st]; }
        __syncthreads();
    }
    if (tid == 0) {
        float S2 = red[0], N0 = red2[0];
        float D = S2 + 1e-8f * (S2 + N0 * __expf(-M));
        rowM[row] = M;
        rowD[row] = 1.f / D;
    }
}

// ---------------- transform bf16 score -> bf16 attn in place ----------------
__global__ void k_wxform(unsigned short* __restrict__ s, const float* __restrict__ thr,
                         const float* __restrict__ rowM, const float* __restrict__ rowD) {
    size_t i = (size_t)blockIdx.x * 256 + threadIdx.x;
    int row = (int)(i >> 9);
    float t = thr[row], M = rowM[row], iD = rowD[row];
    uint4* p = (uint4*)s + i;
    uint4 u = *p;
    unsigned int w[4] = {u.x, u.y, u.z, u.w};
    unsigned int o[4];
#pragma unroll
    for (int q = 0; q < 4; q++) {
        float v0 = __uint_as_float(w[q] << 16);
        float v1 = __uint_as_float(w[q] & 0xFFFF0000u);
        float a0 = (v0 >= t) ? __expf(10.f * v0 - M) * iD : 0.f;
        float a1 = (v1 >= t) ? __expf(10.f * v1 - M) * iD : 0.f;
        o[q] = (unsigned int)f2bf(a0) | ((unsigned int)f2bf(a1) << 16);
    }
    *p = make_uint4(o[0], o[1], o[2], o[3]);
}

// ---------------- fold (overlap-add gather) + divide by cnt -> zi -----------
__global__ void k_fold(const float* __restrict__ agg, float* __restrict__ zi) {
    int p = blockIdx.x * 256 + threadIdx.x;
    int x = p & 255, y = (p >> 8) & 255, ci = (p >> 16) & 15, n = p >> 20;
    int yp = y + 1, xp = x + 1;
    int lh1 = yp >> 2; if (lh1 > 63) lh1 = 63;
    int lh0 = (yp >= 3) ? ((yp - 3) >> 2) : 0;
    int lw1 = xp >> 2; if (lw1 > 63) lw1 = 63;
    int lw0 = (xp >= 3) ? ((xp - 3) >> 2) : 0;
    const float* an = agg + (size_t)n * LL * DINP;
    float sum = 0.f;
    for (int lh = lh0; lh <= lh1; lh++) {
        int dy = yp - 4 * lh;
        for (int lw = lw0; lw <= lw1; lw++) {
            int dx = xp - 4 * lw;
            sum += an[(size_t)(lh * 64 + lw) * DINP + ci * 49 + dy * 7 + dx];
        }
    }
    float cnt = (float)((lh1 - lh0 + 1) * (lw1 - lw0 + 1));
    zi[p] = sum / cnt;
}

// ---------------- final: out = b + zi @ W_w^T + W_b -------------------------
__global__ void k_final(const float* __restrict__ zi, const float* __restrict__ b,
                        const float* __restrict__ W_w, const float* __restrict__ W_b,
                        float* __restrict__ out) {
    __shared__ float w[16 * 64];
    int tid = threadIdx.x;
    for (int i = tid; i < 16 * 64; i += 256) {
        int ci = i >> 6; int co = i & 63;
        w[i] = W_w[co * 16 + ci];
    }
    __syncthreads();
    int p = blockIdx.x * 256 + tid;
    int n = p >> 16, yx = p & 65535;
    float acc[64];
#pragma unroll
    for (int co = 0; co < 64; co++) acc[co] = 0.f;
    const float* zn = zi + (size_t)n * 16 * 65536;
#pragma unroll
    for (int ci = 0; ci < 16; ci++) {
        float v = zn[ci * 65536 + yx];
#pragma unroll
        for (int co = 0; co < 64; co++) acc[co] += v * w[ci * 64 + co];
    }
    const float* bn = b + (size_t)n * 64 * 65536;
    float* on = out + (size_t)n * 64 * 65536;
#pragma unroll
    for (int co = 0; co < 64; co++) on[co * 65536 + yx] = bn[co * 65536 + yx] + acc[co] + W_b[co];
}

extern "C" void kernel_launch(void* const* d_in, const int* in_sizes, int n_in,
                              void* d_out, int out_size, void* d_ws, size_t ws_size,
                              hipStream_t stream) {
    const float* b     = (const float*)d_in[0];
    const float* g_w   = (const float*)d_in[1];
    const float* g_b   = (const float*)d_in[2];
    const float* th_w  = (const float*)d_in[3];
    const float* th_b  = (const float*)d_in[4];
    const float* W_w   = (const float*)d_in[5];
    const float* W_b   = (const float*)d_in[6];
    const float* fc1_w = (const float*)d_in[7];
    const float* fc1_b = (const float*)d_in[8];
    const float* fc2_w = (const float*)d_in[9];
    const float* fc2_b = (const float*)d_in[10];
    const float* thr_w = (const float*)d_in[11];
    const float* thr_b = (const float*)d_in[12];
    // d_in[13], d_in[14] (bias conv): constant along softmax axis -> cancels.
    float* out = (float*)d_out;

    float* ws = (float*)d_ws;
    size_t off = 0;
    auto alloc = [&](size_t nf) { float* p = ws + off; off += (nf + 63) & ~(size_t)63; return p; };
    float* b1   = alloc((size_t)NB * CI * HH * WWD);
    float* b2   = alloc((size_t)NB * CI * HH * WWD);
    float* P    = alloc((size_t)NB * LL * DIN);
    float* agg  = alloc((size_t)NB * LL * DINP);
    unsigned short* piT  = (unsigned short*)alloc((size_t)NB * DINP * LL / 2);
    unsigned short* wifb = (unsigned short*)alloc((size_t)NB * LL * DOUTP / 2);
    unsigned short* xifb = (unsigned short*)alloc((size_t)NB * LL * DOUTP / 2);
    float* thr  = alloc((size_t)NB * LL);
    float* rowM = alloc((size_t)NB * LL);
    float* rowD = alloc((size_t)NB * LL);
    unsigned short* score = (unsigned short*)alloc((size_t)NB * LL * LL / 2);
    float* zi = b1;   // b1 dead after k_patches

    k_conv<<<dim3(NB * 256), 256, 0, stream>>>(b, g_w, g_b, th_w, th_b, b1, b2);
    k_thr<<<dim3(2048), 256, 0, stream>>>(b, thr_w, thr_b, thr);
    k_patches<<<dim3(25088), 256, 0, stream>>>(b1, P);
    k_patchesT<<<dim3(28672), 256, 0, stream>>>(b2, piT);
    k_fcgemm<<<dim3(128, 4), 256, 0, stream>>>(P, fc1_w, fc1_b, fc2_w, fc2_b, wifb, xifb);
    k_gemm_nt<true><<<dim3(32, 32, NB), 256, 0, stream>>>(
        wifb, xifb, (void*)score, DOUTP, DOUTP, LL, DOUTP,
        (size_t)LL * DOUTP, (size_t)LL * DOUTP, (size_t)LL * LL);
    k_rowstats<<<dim3(NB * LL), 256, 0, stream>>>(score, thr, rowM, rowD);
    k_wxform<<<dim3(16384), 256, 0, stream>>>(score, thr, rowM, rowD);
    k_gemm_nt<false><<<dim3(32, DINP / 128, NB), 256, 0, stream>>>(
        score, piT, (void*)agg, LL, LL, DINP, LL,
        (size_t)LL * LL, (size_t)DINP * LL, (size_t)LL * DINP);
    k_fold<<<dim3(8192), 256, 0, stream>>>(agg, zi);
    k_final<<<dim3(512), 256, 0, stream>>>(zi, b, W_w, W_b, out);
}

// Round 4
// 507.250 us; speedup vs baseline: 3.5520x; 1.2336x over previous
//
#include <hip/hip_runtime.h>
#include <math.h>

#define CIN  64
#define CI   16
#define HH   256
#define WWD  256
#define KS   7
#define STR  4
#define LH   64
#define LWD  64
#define LL   4096
#define DIN  784
#define DINP 896     // padded to multiple of 128 (agg N)
#define DKP  832     // DIN padded to multiple of 64 (fc K)
#define DOUT 196
#define DOUTP 256    // padded N for fc / K for score GEMM
#define NB   2

typedef __attribute__((ext_vector_type(8))) short bf16x8;
typedef __attribute__((ext_vector_type(4))) float f32x4;

__device__ __forceinline__ unsigned short f2bf(float x) {
    unsigned int u = __float_as_uint(x);
    unsigned int r = (u + 0x7FFFu + ((u >> 16) & 1u)) >> 16;
    return (unsigned short)r;
}

__device__ __forceinline__ void stage16(const void* g, void* l) {
#if defined(__has_builtin)
#if __has_builtin(__builtin_amdgcn_global_load_lds)
    __builtin_amdgcn_global_load_lds(
        (const __attribute__((address_space(1))) unsigned int*)g,
        (__attribute__((address_space(3))) unsigned int*)l, 16, 0, 0);
    return;
#endif
#endif
    *(float4*)l = *(const float4*)g;
}

// ---------------- prep: repack conv weights for scalar (SGPR) access --------
// wrep[ci][0..143] = g_w[co][ci][t] at t*16+co ; wrep[ci][144..159] = th_w[co][ci]
__global__ void k_prep_w(const float* __restrict__ g_w, const float* __restrict__ th_w,
                         float* __restrict__ wrep) {
    int i = blockIdx.x * 256 + threadIdx.x;
    if (i >= 64 * 160) return;
    int ci = i / 160, r = i % 160;
    float v;
    if (r < 144) { int t = r >> 4, co = r & 15; v = g_w[(co * 64 + ci) * 9 + t]; }
    else         { int co = r - 144;            v = th_w[co * 64 + ci]; }
    wrep[i] = v;
}

// ---------------- prep: fc weights -> bf16 [f][256][832], zero-padded -------
__global__ void k_prep_fc(const float* __restrict__ fc1_w, const float* __restrict__ fc2_w,
                          unsigned short* __restrict__ fcwb) {
    int i = blockIdx.x * 256 + threadIdx.x;
    if (i >= 2 * DOUTP * DKP) return;
    int col = i % DKP; int row = (i / DKP) % DOUTP; int f = i / (DKP * DOUTP);
    float v = 0.f;
    if (row < DOUT && col < DIN) v = (f ? fc2_w : fc1_w)[row * DIN + col];
    fcwb[i] = f2bf(v);
}

// ---------------- conv3x3 (g) + conv1x1 (theta): scalar weights -------------
__global__ __launch_bounds__(256) void k_conv(
        const float* __restrict__ b, const float* __restrict__ wrep,
        const float* __restrict__ g_b, const float* __restrict__ th_b,
        float* __restrict__ b1, float* __restrict__ b2) {
    int n = blockIdx.x >> 8;
    int p = ((blockIdx.x & 255) << 8) + threadIdx.x;
    int y = p >> 8, x = p & 255;
    bool xm = x > 0, xp = x < 255, ym = y > 0, yp = y < 255;
    float acc1[16], acc2[16];
#pragma unroll
    for (int co = 0; co < 16; co++) { acc1[co] = g_b[co]; acc2[co] = th_b[co]; }
    const float* bn = b + (size_t)n * 64 * 65536 + p;
#pragma unroll 2
    for (int ci = 0; ci < 64; ci++) {
        const float* bc = bn + ci * 65536;
        float v[9];
        v[0] = (ym && xm) ? bc[-257] : 0.f;
        v[1] = ym ? bc[-256] : 0.f;
        v[2] = (ym && xp) ? bc[-255] : 0.f;
        v[3] = xm ? bc[-1] : 0.f;
        v[4] = bc[0];
        v[5] = xp ? bc[1] : 0.f;
        v[6] = (yp && xm) ? bc[255] : 0.f;
        v[7] = yp ? bc[256] : 0.f;
        v[8] = (yp && xp) ? bc[257] : 0.f;
        const float* wc = wrep + ci * 160;   // uniform index -> s_load
#pragma unroll
        for (int t = 0; t < 9; t++) {
            float vt = v[t];
#pragma unroll
            for (int co = 0; co < 16; co++) acc1[co] = fmaf(vt, wc[t * 16 + co], acc1[co]);
        }
        float vc = v[4];
#pragma unroll
        for (int co = 0; co < 16; co++) acc2[co] = fmaf(vc, wc[144 + co], acc2[co]);
    }
    float* o1 = b1 + (size_t)n * 16 * 65536;
    float* o2 = b2 + (size_t)n * 16 * 65536;
#pragma unroll
    for (int co = 0; co < 16; co++) { o1[co * 65536 + p] = acc1[co]; o2[co * 65536 + p] = acc2[co]; }
}

// ---------------- thr: 7x7 stride-4 conv, one WAVE per output, lane = ci ----
__global__ __launch_bounds__(256) void k_thr(
        const float* __restrict__ b, const float* __restrict__ thr_w,
        const float* __restrict__ thr_b, float* __restrict__ thr) {
    __shared__ float w[64 * 49];
    int tid = threadIdx.x;
    for (int i = tid; i < 64 * 49; i += 256) w[i] = thr_w[i];
    __syncthreads();
    int wid = (blockIdx.x << 2) + (tid >> 6);
    int lane = tid & 63;
    int n = wid >> 12, l = wid & 4095;
    int lh = (l >> 6), lw = l & 63;
    const float* bc = b + (size_t)(n * 64 + lane) * 65536;
    const float* wl = w + lane * 49;
    float acc = 0.f;
#pragma unroll
    for (int dy = 0; dy < 7; dy++) {
        int y = lh * 4 + dy - 1;
        if (y < 0 || y > 255) continue;
        const float* br = bc + y * 256;
#pragma unroll
        for (int dx = 0; dx < 7; dx++) {
            int x = lw * 4 + dx - 1;
            if (x < 0 || x > 255) continue;
            acc += br[x] * wl[dy * 7 + dx];
        }
    }
#pragma unroll
    for (int off = 32; off > 0; off >>= 1) acc += __shfl_down(acc, off, 64);
    if (lane == 0) thr[wid] = acc + thr_b[0];
}

// ---------------- patches of b1 -> Pb bf16 [n][l][DKP], zero-padded ---------
__global__ void k_patchesA(const float* __restrict__ b1, unsigned short* __restrict__ Pb) {
    size_t e = (size_t)blockIdx.x * 256 + threadIdx.x;
    if (e >= (size_t)NB * LL * DKP) return;
    int d = (int)(e % DKP); size_t r = e / DKP;
    int l = (int)(r & 4095); int n = (int)(r >> 12);
    float v = 0.f;
    if (d < DIN) {
        int ci = d / 49; int t = d % 49; int dy = t / 7; int dx = t % 7;
        int y = (l >> 6) * 4 + dy - 1, x = (l & 63) * 4 + dx - 1;
        if (y >= 0 && y < 256 && x >= 0 && x < 256)
            v = b1[((size_t)(n * 16 + ci) * 256 + y) * 256 + x];
    }
    Pb[e] = f2bf(v);
}

// ---------------- patches of b2 -> piT bf16 [n][d][l], d padded to DINP -----
__global__ void k_patchesT(const float* __restrict__ b2, unsigned short* __restrict__ piT) {
    size_t e = (size_t)blockIdx.x * 256 + threadIdx.x;
    int l = (int)(e & 4095);
    int d = (int)((e >> 12) % DINP);
    int n = (int)(e / ((size_t)DINP * LL));
    float v = 0.f;
    if (d < DIN) {
        int ci = d / 49; int t = d % 49; int dy = t / 7; int dx = t % 7;
        int y = (l >> 6) * 4 + dy - 1, x = (l & 63) * 4 + dx - 1;
        if (y >= 0 && y < 256 && x >= 0 && x < 256)
            v = b2[((size_t)(n * 16 + ci) * 256 + y) * 256 + x];
    }
    piT[e] = f2bf(v);
}

// ---------------- MFMA GEMM (NT): C[MxN] = A[MxK] * Bt[NxK]^T ---------------
// MODE 0: store fp32. MODE 1: store bf16. MODE 2: fc epilogue
//   (z = n*2+f ; A off (z>>1)*sA ; B off (z&1)*sB ; bias+relu, bf16, zero col>=196)
template<int MODE>
__global__ __launch_bounds__(256) void k_gemm_nt(
        const unsigned short* __restrict__ A, const unsigned short* __restrict__ Bt,
        void* __restrict__ C, int lda, int ldb, int ldc, int K,
        size_t sA, size_t sB, size_t sC,
        const float* __restrict__ bias1, const float* __restrict__ bias2) {
    __shared__ unsigned short lA[128 * 64];
    __shared__ unsigned short lB[128 * 64];
    int tid = threadIdx.x;
    int wave = tid >> 6, lane = tid & 63;
    int lr = lane & 15, lq = lane >> 4;
    int wm = (wave >> 1) * 64, wn = (wave & 1) * 64;
    int i0 = blockIdx.x * 128, j0 = blockIdx.y * 128;
    int z = blockIdx.z;
    int az = (MODE == 2) ? (z >> 1) : z;
    int bz = (MODE == 2) ? (z & 1) : z;
    const unsigned short* Ab = A + (size_t)az * sA + (size_t)i0 * lda;
    const unsigned short* Bb = Bt + (size_t)bz * sB + (size_t)j0 * ldb;
    f32x4 acc[4][4] = {};
    for (int k0 = 0; k0 < K; k0 += 64) {
        __syncthreads();
#pragma unroll
        for (int it = 0; it < 4; it++) {
            int c = it * 256 + tid;
            int row = c >> 3, slot = c & 7;
            int col8 = slot ^ (row & 7);
            stage16(Ab + (size_t)row * lda + k0 + col8 * 8, &lA[c * 8]);
        }
#pragma unroll
        for (int it = 0; it < 4; it++) {
            int c = it * 256 + tid;
            int row = c >> 3, slot = c & 7;
            int col8 = slot ^ (row & 7);
            stage16(Bb + (size_t)row * ldb + k0 + col8 * 8, &lB[c * 8]);
        }
        __syncthreads();
#pragma unroll
        for (int ks = 0; ks < 2; ks++) {
            bf16x8 af[4], bfr[4];
#pragma unroll
            for (int t = 0; t < 4; t++) {
                int row = wm + t * 16 + lr;
                int slot = ks * 4 + lq;
                af[t] = *(const bf16x8*)&lA[row * 64 + (slot ^ (row & 7)) * 8];
            }
#pragma unroll
            for (int t = 0; t < 4; t++) {
                int row = wn + t * 16 + lr;
                int slot = ks * 4 + lq;
                bfr[t] = *(const bf16x8*)&lB[row * 64 + (slot ^ (row & 7)) * 8];
            }
#pragma unroll
            for (int mi = 0; mi < 4; mi++)
#pragma unroll
                for (int nj = 0; nj < 4; nj++)
                    acc[mi][nj] = __builtin_amdgcn_mfma_f32_16x16x32_bf16(
                        af[mi], bfr[nj], acc[mi][nj], 0, 0, 0);
        }
    }
    if (MODE == 0) {
        float* Cf = (float*)C + (size_t)z * sC;
#pragma unroll
        for (int mi = 0; mi < 4; mi++)
#pragma unroll
            for (int r = 0; r < 4; r++) {
                int row = i0 + wm + mi * 16 + lq * 4 + r;
#pragma unroll
                for (int nj = 0; nj < 4; nj++)
                    Cf[(size_t)row * ldc + j0 + wn + nj * 16 + lr] = acc[mi][nj][r];
            }
    } else if (MODE == 1) {
        unsigned short* Cb = (unsigned short*)C + (size_t)z * sC;
#pragma unroll
        for (int mi = 0; mi < 4; mi++)
#pragma unroll
            for (int r = 0; r < 4; r++) {
                int row = i0 + wm + mi * 16 + lq * 4 + r;
#pragma unroll
                for (int nj = 0; nj < 4; nj++)
                    Cb[(size_t)row * ldc + j0 + wn + nj * 16 + lr] = f2bf(acc[mi][nj][r]);
            }
    } else {
        const float* biasp = bz ? bias2 : bias1;
        unsigned short* Cb = (unsigned short*)C + (size_t)z * sC;
#pragma unroll
        for (int mi = 0; mi < 4; mi++)
#pragma unroll
            for (int r = 0; r < 4; r++) {
                int row = i0 + wm + mi * 16 + lq * 4 + r;
#pragma unroll
                for (int nj = 0; nj < 4; nj++) {
                    int col = j0 + wn + nj * 16 + lr;
                    float bv = (col < DOUT) ? biasp[col] : 0.f;
                    float v = fmaxf(acc[mi][nj][r] + bv, 0.f);
                    Cb[(size_t)row * ldc + col] = f2bf(v);   // col>=196: acc=0,b=0 -> 0
                }
            }
    }
}

// ---------------- per-row softmax stats over bf16 score ---------------------
__global__ void k_rowstats(const unsigned short* __restrict__ score, const float* __restrict__ thr,
                           float* __restrict__ rowM, float* __restrict__ rowD) {
    __shared__ float red[256], red2[256];
    int row = blockIdx.x;
    int tid = threadIdx.x;
    const uint4* s4 = (const uint4*)(score + (size_t)row * LL);
    float t = thr[row];
    float mx = 0.f;
    for (int c = tid; c < 512; c += 256) {
        uint4 u = s4[c];
        unsigned int w[4] = {u.x, u.y, u.z, u.w};
#pragma unroll
        for (int q = 0; q < 4; q++) {
            float v0 = __uint_as_float(w[q] << 16);
            float v1 = __uint_as_float(w[q] & 0xFFFF0000u);
            if (v0 >= t) mx = fmaxf(mx, v0);
            if (v1 >= t) mx = fmaxf(mx, v1);
        }
    }
    red[tid] = mx; __syncthreads();
    for (int st = 128; st > 0; st >>= 1) {
        if (tid < st) red[tid] = fmaxf(red[tid], red[tid + st]);
        __syncthreads();
    }
    float M = 10.f * fmaxf(red[0], 0.f);
    __syncthreads();
    float s2 = 0.f, n0 = 0.f;
    for (int c = tid; c < 512; c += 256) {
        uint4 u = s4[c];
        unsigned int w[4] = {u.x, u.y, u.z, u.w};
#pragma unroll
        for (int q = 0; q < 4; q++) {
            float v0 = __uint_as_float(w[q] << 16);
            float v1 = __uint_as_float(w[q] & 0xFFFF0000u);
            if (v0 >= t) s2 += __expf(10.f * v0 - M); else n0 += 1.f;
            if (v1 >= t) s2 += __expf(10.f * v1 - M); else n0 += 1.f;
        }
    }
    red[tid] = s2; red2[tid] = n0; __syncthreads();
    for (int st = 128; st > 0; st >>= 1) {
        if (tid < st) { red[tid] += red[tid + st]; red2[tid] += red2[tid + st]; }
        __syncthreads();
    }
    if (tid == 0) {
        float S2 = red[0], N0 = red2[0];
        float D = S2 + 1e-8f * (S2 + N0 * __expf(-M));
        rowM[row] = M;
        rowD[row] = 1.f / D;
    }
}

// ---------------- transform bf16 score -> bf16 attn in place ----------------
__global__ void k_wxform(unsigned short* __restrict__ s, const float* __restrict__ thr,
                         const float* __restrict__ rowM, const float* __restrict__ rowD) {
    size_t i = (size_t)blockIdx.x * 256 + threadIdx.x;
    int row = (int)(i >> 9);
    float t = thr[row], M = rowM[row], iD = rowD[row];
    uint4* p = (uint4*)s + i;
    uint4 u = *p;
    unsigned int w[4] = {u.x, u.y, u.z, u.w};
    unsigned int o[4];
#pragma unroll
    for (int q = 0; q < 4; q++) {
        float v0 = __uint_as_float(w[q] << 16);
        float v1 = __uint_as_float(w[q] & 0xFFFF0000u);
        float a0 = (v0 >= t) ? __expf(10.f * v0 - M) * iD : 0.f;
        float a1 = (v1 >= t) ? __expf(10.f * v1 - M) * iD : 0.f;
        o[q] = (unsigned int)f2bf(a0) | ((unsigned int)f2bf(a1) << 16);
    }
    *p = make_uint4(o[0], o[1], o[2], o[3]);
}

// ---------------- fold (overlap-add gather) + divide by cnt -> zi -----------
__global__ void k_fold(const float* __restrict__ agg, float* __restrict__ zi) {
    int p = blockIdx.x * 256 + threadIdx.x;
    int x = p & 255, y = (p >> 8) & 255, ci = (p >> 16) & 15, n = p >> 20;
    int yp = y + 1, xp = x + 1;
    int lh1 = yp >> 2; if (lh1 > 63) lh1 = 63;
    int lh0 = (yp >= 3) ? ((yp - 3) >> 2) : 0;
    int lw1 = xp >> 2; if (lw1 > 63) lw1 = 63;
    int lw0 = (xp >= 3) ? ((xp - 3) >> 2) : 0;
    const float* an = agg + (size_t)n * LL * DINP;
    float sum = 0.f;
    for (int lh = lh0; lh <= lh1; lh++) {
        int dy = yp - 4 * lh;
        for (int lw = lw0; lw <= lw1; lw++) {
            int dx = xp - 4 * lw;
            sum += an[(size_t)(lh * 64 + lw) * DINP + ci * 49 + dy * 7 + dx];
        }
    }
    float cnt = (float)((lh1 - lh0 + 1) * (lw1 - lw0 + 1));
    zi[p] = sum / cnt;
}

// ---------------- final: out = b + zi @ W_w^T + W_b -------------------------
__global__ void k_final(const float* __restrict__ zi, const float* __restrict__ b,
                        const float* __restrict__ W_w, const float* __restrict__ W_b,
                        float* __restrict__ out) {
    __shared__ float w[16 * 64];
    int tid = threadIdx.x;
    for (int i = tid; i < 16 * 64; i += 256) {
        int ci = i >> 6; int co = i & 63;
        w[i] = W_w[co * 16 + ci];
    }
    __syncthreads();
    int p = blockIdx.x * 256 + tid;
    int n = p >> 16, yx = p & 65535;
    float acc[64];
#pragma unroll
    for (int co = 0; co < 64; co++) acc[co] = 0.f;
    const float* zn = zi + (size_t)n * 16 * 65536;
#pragma unroll
    for (int ci = 0; ci < 16; ci++) {
        float v = zn[ci * 65536 + yx];
#pragma unroll
        for (int co = 0; co < 64; co++) acc[co] += v * w[ci * 64 + co];
    }
    const float* bn = b + (size_t)n * 64 * 65536;
    float* on = out + (size_t)n * 64 * 65536;
#pragma unroll
    for (int co = 0; co < 64; co++) on[co * 65536 + yx] = bn[co * 65536 + yx] + acc[co] + W_b[co];
}

extern "C" void kernel_launch(void* const* d_in, const int* in_sizes, int n_in,
                              void* d_out, int out_size, void* d_ws, size_t ws_size,
                              hipStream_t stream) {
    const float* b     = (const float*)d_in[0];
    const float* g_w   = (const float*)d_in[1];
    const float* g_b   = (const float*)d_in[2];
    const float* th_w  = (const float*)d_in[3];
    const float* th_b  = (const float*)d_in[4];
    const float* W_w   = (const float*)d_in[5];
    const float* W_b   = (const float*)d_in[6];
    const float* fc1_w = (const float*)d_in[7];
    const float* fc1_b = (const float*)d_in[8];
    const float* fc2_w = (const float*)d_in[9];
    const float* fc2_b = (const float*)d_in[10];
    const float* thr_w = (const float*)d_in[11];
    const float* thr_b = (const float*)d_in[12];
    // d_in[13], d_in[14] (bias conv): constant along softmax axis -> cancels.
    float* out = (float*)d_out;

    float* ws = (float*)d_ws;
    size_t off = 0;
    auto alloc = [&](size_t nf) { float* p = ws + off; off += (nf + 63) & ~(size_t)63; return p; };
    float* b1   = alloc((size_t)NB * CI * HH * WWD);
    float* b2   = alloc((size_t)NB * CI * HH * WWD);
    float* agg  = alloc((size_t)NB * LL * DINP);
    unsigned short* Pb    = (unsigned short*)alloc((size_t)NB * LL * DKP / 2);
    unsigned short* piT   = (unsigned short*)alloc((size_t)NB * DINP * LL / 2);
    unsigned short* fcout = (unsigned short*)alloc((size_t)NB * 2 * LL * DOUTP / 2);
    float* wrep = alloc(64 * 160);
    unsigned short* fcwb = (unsigned short*)alloc((size_t)2 * DOUTP * DKP / 2);
    float* thr  = alloc((size_t)NB * LL);
    float* rowM = alloc((size_t)NB * LL);
    float* rowD = alloc((size_t)NB * LL);
    unsigned short* score = (unsigned short*)alloc((size_t)NB * LL * LL / 2);
    float* zi = b1;   // b1 dead after k_patchesA

    k_prep_w<<<dim3(40), 256, 0, stream>>>(g_w, th_w, wrep);
    k_prep_fc<<<dim3((2 * DOUTP * DKP + 255) / 256), 256, 0, stream>>>(fc1_w, fc2_w, fcwb);
    k_conv<<<dim3(NB * 256), 256, 0, stream>>>(b, wrep, g_b, th_b, b1, b2);
    k_thr<<<dim3(2048), 256, 0, stream>>>(b, thr_w, thr_b, thr);
    k_patchesA<<<dim3((int)((size_t)NB * LL * DKP / 256)), 256, 0, stream>>>(b1, Pb);
    k_patchesT<<<dim3((int)((size_t)NB * DINP * LL / 256)), 256, 0, stream>>>(b2, piT);
    // FC: wif/xif = relu(Pb @ fcwb^T + bias) -> fcout[z=n*2+f][4096][256] bf16
    k_gemm_nt<2><<<dim3(32, 2, 4), 256, 0, stream>>>(
        Pb, fcwb, (void*)fcout, DKP, DKP, DOUTP, DKP,
        (size_t)LL * DKP, (size_t)DOUTP * DKP, (size_t)LL * DOUTP, fc1_b, fc2_b);
    // score[l][m] = wif[l].xif[m]  (bf16 out); wif = fcout[n*2+0], xif = fcout[n*2+1]
    k_gemm_nt<1><<<dim3(32, 32, NB), 256, 0, stream>>>(
        fcout, fcout + (size_t)LL * DOUTP, (void*)score, DOUTP, DOUTP, LL, DOUTP,
        (size_t)2 * LL * DOUTP, (size_t)2 * LL * DOUTP, (size_t)LL * LL, nullptr, nullptr);
    k_rowstats<<<dim3(NB * LL), 256, 0, stream>>>(score, thr, rowM, rowD);
    k_wxform<<<dim3(16384), 256, 0, stream>>>(score, thr, rowM, rowD);
    // agg[l][d] = sum_m attn[l][m] * piT[d][m]  (fp32 out)
    k_gemm_nt<0><<<dim3(32, DINP / 128, NB), 256, 0, stream>>>(
        score, piT, (void*)agg, LL, LL, DINP, LL,
        (size_t)LL * LL, (size_t)DINP * LL, (size_t)LL * DINP, nullptr, nullptr);
    k_fold<<<dim3(8192), 256, 0, stream>>>(agg, zi);
    k_final<<<dim3(512), 256, 0, stream>>>(zi, b, W_w, W_b, out);
}

// Round 5
// 432.798 us; speedup vs baseline: 4.1630x; 1.1720x over previous
//
#include <hip/hip_runtime.h>
#include <math.h>

#define CIN  64
#define CI   16
#define HH   256
#define WWD  256
#define KS   7
#define STR  4
#define LH   64
#define LWD  64
#define LL   4096
#define DIN  784
#define DINP 896     // padded to multiple of 128 (agg N)
#define DKP  832     // DIN padded to multiple of 64 (fc K)
#define DOUT 196
#define DOUTP 256    // padded N for fc / K for score GEMM
#define NB   2
#define YP   258     // padded rows in bTp
#define XP   264     // padded cols in bTp

typedef __attribute__((ext_vector_type(8))) short bf16x8;
typedef __attribute__((ext_vector_type(4))) float f32x4;

__device__ __forceinline__ unsigned short f2bf(float x) {
    unsigned int u = __float_as_uint(x);
    unsigned int r = (u + 0x7FFFu + ((u >> 16) & 1u)) >> 16;
    return (unsigned short)r;
}

__device__ __forceinline__ void stage16(const void* g, void* l) {
#if defined(__has_builtin)
#if __has_builtin(__builtin_amdgcn_global_load_lds)
    __builtin_amdgcn_global_load_lds(
        (const __attribute__((address_space(1))) unsigned int*)g,
        (__attribute__((address_space(3))) unsigned int*)l, 16, 0, 0);
    return;
#endif
#endif
    *(float4*)l = *(const float4*)g;
}

// ---- prep: b (fp32 NCHW) -> bTp bf16 [n][y+1][s=ci/8][x+4][j=ci%8], padded -
__global__ __launch_bounds__(256) void k_prep_b(const float* __restrict__ b,
                                                unsigned short* __restrict__ bTp) {
    int blk = blockIdx.x;            // n*YP*8 blocks
    int s = blk & 7; int yy = (blk >> 3) % YP; int n = blk / (8 * YP);
    int y = yy - 1;
    for (int xx = threadIdx.x; xx < XP; xx += 256) {
        int x = xx - 4;
        bool v = (y >= 0 && y < 256 && x >= 0 && x < 256);
        unsigned short h[8];
#pragma unroll
        for (int j = 0; j < 8; j++)
            h[j] = v ? f2bf(b[((size_t)(n * 64 + s * 8 + j) * 256 + y) * 256 + x]) : (unsigned short)0;
        *(uint4*)&bTp[((((size_t)n * YP + yy) * 8 + s) * XP + xx) * 8] = *(uint4*)h;
    }
}

// ---- prep: conv weights -> wbt[t][h][q][co32][j8] bf16 (g: co<16; theta: co>=16, t==4 only)
__global__ void k_prep_wb(const float* __restrict__ g_w, const float* __restrict__ th_w,
                          unsigned short* __restrict__ wbt) {
    int i = blockIdx.x * 256 + threadIdx.x;
    if (i >= 18432) return;
    int j = i & 7, co = (i >> 3) & 31, q = (i >> 8) & 3, h = (i >> 10) & 1, t = i >> 11;
    int ci = h * 32 + q * 8 + j;
    float v;
    if (co < 16) v = g_w[((size_t)co * 64 + ci) * 9 + t];
    else         v = (t == 4) ? th_w[(size_t)(co - 16) * 64 + ci] : 0.f;
    wbt[i] = f2bf(v);
}

// ---- prep: fc weights -> bf16 [f][256][832], zero-padded -------------------
__global__ void k_prep_fc(const float* __restrict__ fc1_w, const float* __restrict__ fc2_w,
                          unsigned short* __restrict__ fcwb) {
    int i = blockIdx.x * 256 + threadIdx.x;
    if (i >= 2 * DOUTP * DKP) return;
    int col = i % DKP; int row = (i / DKP) % DOUTP; int f = i / (DKP * DOUTP);
    float v = 0.f;
    if (row < DOUT && col < DIN) v = (f ? fc2_w : fc1_w)[row * DIN + col];
    fcwb[i] = f2bf(v);
}

// ---- MFMA implicit-GEMM conv: bx[n][y][x][co32] = {g-conv | theta-conv} ----
// one block per image row; 4 waves * 16 pixels = 64-pixel strips, 4 strips.
__global__ __launch_bounds__(256) void k_convm(
        const unsigned short* __restrict__ bTp, const unsigned short* __restrict__ wbt,
        const float* __restrict__ g_b, const float* __restrict__ th_b,
        unsigned short* __restrict__ bx) {
    __shared__ unsigned short wb[18432];       // 36 KB weights
    __shared__ unsigned short ti[8 * 3 * 68 * 8];  // 26 KB input tile [s][r][68 c][8 j]
    int tid = threadIdx.x;
#pragma unroll
    for (int i = 0; i < 9; i++) {              // 2304 chunks of 16B
        int c = i * 256 + tid;
        stage16(wbt + (size_t)c * 8, &wb[c * 8]);
    }
    int n = blockIdx.x >> 8, y = blockIdx.x & 255;
    int wave = tid >> 6, lane = tid & 63, lr = lane & 15, q = lane >> 4;
    int m0 = wave * 16;
    float bg = g_b[lr], bt = th_b[lr];
    for (int xs = 0; xs < 4; xs++) {
        __syncthreads();                        // ti safe to overwrite (and wb ready)
        int x0 = xs * 64;
#pragma unroll
        for (int i = 0; i < 7; i++) {          // 1632 chunks of 16B
            int c = i * 256 + tid;
            if (c < 1632) {
                int s = c / 204; int rem = c % 204; int r = rem / 68; int cc = rem % 68;
                const unsigned short* src =
                    bTp + ((((size_t)n * YP + y + r) * 8 + s) * XP + (x0 + 3 + cc)) * 8;
                stage16(src, &ti[c * 8]);
            }
        }
        __syncthreads();
        f32x4 a0 = {bg, bg, bg, bg}, a1 = {bt, bt, bt, bt};
#pragma unroll
        for (int t = 0; t < 9; t++) {
            int dy = t / 3, dx = t % 3;
#pragma unroll
            for (int h = 0; h < 2; h++) {
                int s = h * 4 + q;
                bf16x8 av = *(const bf16x8*)&ti[(((s * 3 + dy) * 68) + m0 + lr + dx) * 8];
                bf16x8 b0 = *(const bf16x8*)&wb[((((t * 2 + h) * 4 + q) * 32) + lr) * 8];
                bf16x8 b1 = *(const bf16x8*)&wb[((((t * 2 + h) * 4 + q) * 32) + 16 + lr) * 8];
                a0 = __builtin_amdgcn_mfma_f32_16x16x32_bf16(av, b0, a0, 0, 0, 0);
                a1 = __builtin_amdgcn_mfma_f32_16x16x32_bf16(av, b1, a1, 0, 0, 0);
            }
        }
        size_t pb = (((size_t)n * 256 + y) * 256 + x0 + m0 + q * 4);
#pragma unroll
        for (int r = 0; r < 4; r++) {
            bx[(pb + r) * 32 + lr]      = f2bf(a0[r]);
            bx[(pb + r) * 32 + 16 + lr] = f2bf(a1[r]);
        }
    }
}

// ---- thr: 7x7 stride-4 conv, one WAVE per output, lane = ci ----------------
__global__ __launch_bounds__(256) void k_thr(
        const float* __restrict__ b, const float* __restrict__ thr_w,
        const float* __restrict__ thr_b, float* __restrict__ thr) {
    __shared__ float w[64 * 49];
    int tid = threadIdx.x;
    for (int i = tid; i < 64 * 49; i += 256) w[i] = thr_w[i];
    __syncthreads();
    int wid = (blockIdx.x << 2) + (tid >> 6);
    int lane = tid & 63;
    int n = wid >> 12, l = wid & 4095;
    int lh = (l >> 6), lw = l & 63;
    const float* bc = b + (size_t)(n * 64 + lane) * 65536;
    const float* wl = w + lane * 49;
    float acc = 0.f;
#pragma unroll
    for (int dy = 0; dy < 7; dy++) {
        int y = lh * 4 + dy - 1;
        if (y < 0 || y > 255) continue;
        const float* br = bc + y * 256;
#pragma unroll
        for (int dx = 0; dx < 7; dx++) {
            int x = lw * 4 + dx - 1;
            if (x < 0 || x > 255) continue;
            acc += br[x] * wl[dy * 7 + dx];
        }
    }
#pragma unroll
    for (int off = 32; off > 0; off >>= 1) acc += __shfl_down(acc, off, 64);
    if (lane == 0) thr[wid] = acc + thr_b[0];
}

// ---- patches of bx(co<16) -> Pb bf16 [n][l][DKP], zero-padded --------------
__global__ void k_patchesA(const unsigned short* __restrict__ bx, unsigned short* __restrict__ Pb) {
    size_t e = (size_t)blockIdx.x * 256 + threadIdx.x;
    if (e >= (size_t)NB * LL * DKP) return;
    int d = (int)(e % DKP); size_t r = e / DKP;
    int l = (int)(r & 4095); int n = (int)(r >> 12);
    unsigned short v = 0;
    if (d < DIN) {
        int ci = d / 49; int t = d % 49; int dy = t / 7; int dx = t % 7;
        int y = (l >> 6) * 4 + dy - 1, x = (l & 63) * 4 + dx - 1;
        if (y >= 0 && y < 256 && x >= 0 && x < 256)
            v = bx[(((size_t)n * 256 + y) * 256 + x) * 32 + ci];
    }
    Pb[e] = v;
}

// ---- patches of bx(co>=16) -> piT bf16 [n][d][l], d padded to DINP ---------
__global__ void k_patchesT(const unsigned short* __restrict__ bx, unsigned short* __restrict__ piT) {
    size_t e = (size_t)blockIdx.x * 256 + threadIdx.x;
    int l = (int)(e & 4095);
    int d = (int)((e >> 12) % DINP);
    int n = (int)(e / ((size_t)DINP * LL));
    unsigned short v = 0;
    if (d < DIN) {
        int ci = d / 49; int t = d % 49; int dy = t / 7; int dx = t % 7;
        int y = (l >> 6) * 4 + dy - 1, x = (l & 63) * 4 + dx - 1;
        if (y >= 0 && y < 256 && x >= 0 && x < 256)
            v = bx[(((size_t)n * 256 + y) * 256 + x) * 32 + 16 + ci];
    }
    piT[e] = v;
}

// ---- MFMA GEMM (NT): C[MxN] = A[MxK] * Bt[NxK]^T ---------------------------
// MODE 0: fp32 out. MODE 1: bf16 out. MODE 2: fc epilogue (bias+relu, bf16)
template<int MODE>
__global__ __launch_bounds__(256) void k_gemm_nt(
        const unsigned short* __restrict__ A, const unsigned short* __restrict__ Bt,
        void* __restrict__ C, int lda, int ldb, int ldc, int K,
        size_t sA, size_t sB, size_t sC,
        const float* __restrict__ bias1, const float* __restrict__ bias2) {
    __shared__ unsigned short lA[128 * 64];
    __shared__ unsigned short lB[128 * 64];
    int tid = threadIdx.x;
    int wave = tid >> 6, lane = tid & 63;
    int lr = lane & 15, lq = lane >> 4;
    int wm = (wave >> 1) * 64, wn = (wave & 1) * 64;
    int i0 = blockIdx.x * 128, j0 = blockIdx.y * 128;
    int z = blockIdx.z;
    int az = (MODE == 2) ? (z >> 1) : z;
    int bz = (MODE == 2) ? (z & 1) : z;
    const unsigned short* Ab = A + (size_t)az * sA + (size_t)i0 * lda;
    const unsigned short* Bb = Bt + (size_t)bz * sB + (size_t)j0 * ldb;
    f32x4 acc[4][4] = {};
    for (int k0 = 0; k0 < K; k0 += 64) {
        __syncthreads();
#pragma unroll
        for (int it = 0; it < 4; it++) {
            int c = it * 256 + tid;
            int row = c >> 3, slot = c & 7;
            int col8 = slot ^ (row & 7);
            stage16(Ab + (size_t)row * lda + k0 + col8 * 8, &lA[c * 8]);
        }
#pragma unroll
        for (int it = 0; it < 4; it++) {
            int c = it * 256 + tid;
            int row = c >> 3, slot = c & 7;
            int col8 = slot ^ (row & 7);
            stage16(Bb + (size_t)row * ldb + k0 + col8 * 8, &lB[c * 8]);
        }
        __syncthreads();
#pragma unroll
        for (int ks = 0; ks < 2; ks++) {
            bf16x8 af[4], bfr[4];
#pragma unroll
            for (int t = 0; t < 4; t++) {
                int row = wm + t * 16 + lr;
                int slot = ks * 4 + lq;
                af[t] = *(const bf16x8*)&lA[row * 64 + (slot ^ (row & 7)) * 8];
            }
#pragma unroll
            for (int t = 0; t < 4; t++) {
                int row = wn + t * 16 + lr;
                int slot = ks * 4 + lq;
                bfr[t] = *(const bf16x8*)&lB[row * 64 + (slot ^ (row & 7)) * 8];
            }
#pragma unroll
            for (int mi = 0; mi < 4; mi++)
#pragma unroll
                for (int nj = 0; nj < 4; nj++)
                    acc[mi][nj] = __builtin_amdgcn_mfma_f32_16x16x32_bf16(
                        af[mi], bfr[nj], acc[mi][nj], 0, 0, 0);
        }
    }
    if (MODE == 0) {
        float* Cf = (float*)C + (size_t)z * sC;
#pragma unroll
        for (int mi = 0; mi < 4; mi++)
#pragma unroll
            for (int r = 0; r < 4; r++) {
                int row = i0 + wm + mi * 16 + lq * 4 + r;
#pragma unroll
                for (int nj = 0; nj < 4; nj++)
                    Cf[(size_t)row * ldc + j0 + wn + nj * 16 + lr] = acc[mi][nj][r];
            }
    } else if (MODE == 1) {
        unsigned short* Cb = (unsigned short*)C + (size_t)z * sC;
#pragma unroll
        for (int mi = 0; mi < 4; mi++)
#pragma unroll
            for (int r = 0; r < 4; r++) {
                int row = i0 + wm + mi * 16 + lq * 4 + r;
#pragma unroll
                for (int nj = 0; nj < 4; nj++)
                    Cb[(size_t)row * ldc + j0 + wn + nj * 16 + lr] = f2bf(acc[mi][nj][r]);
            }
    } else {
        const float* biasp = bz ? bias2 : bias1;
        unsigned short* Cb = (unsigned short*)C + (size_t)z * sC;
#pragma unroll
        for (int mi = 0; mi < 4; mi++)
#pragma unroll
            for (int r = 0; r < 4; r++) {
                int row = i0 + wm + mi * 16 + lq * 4 + r;
#pragma unroll
                for (int nj = 0; nj < 4; nj++) {
                    int col = j0 + wn + nj * 16 + lr;
                    float bv = (col < DOUT) ? biasp[col] : 0.f;
                    float v = fmaxf(acc[mi][nj][r] + bv, 0.f);
                    Cb[(size_t)row * ldc + col] = f2bf(v);
                }
            }
    }
}

// ---- fused masked-softmax over one score row (stats + transform) -----------
__global__ __launch_bounds__(256) void k_softmax(
        unsigned short* __restrict__ score, const float* __restrict__ thr) {
    __shared__ uint4 srow[512];             // 4096 bf16
    __shared__ float red[256], red2[256];
    int row = blockIdx.x, tid = threadIdx.x;
    uint4* g4 = (uint4*)(score + (size_t)row * LL);
    float t = thr[row];
    float mx = 0.f;
#pragma unroll
    for (int c = tid; c < 512; c += 256) {
        uint4 u = g4[c];
        srow[c] = u;
        unsigned int w[4] = {u.x, u.y, u.z, u.w};
#pragma unroll
        for (int qq = 0; qq < 4; qq++) {
            float v0 = __uint_as_float(w[qq] << 16);
            float v1 = __uint_as_float(w[qq] & 0xFFFF0000u);
            if (v0 >= t) mx = fmaxf(mx, v0);
            if (v1 >= t) mx = fmaxf(mx, v1);
        }
    }
    red[tid] = mx; __syncthreads();
    for (int st = 128; st > 0; st >>= 1) {
        if (tid < st) red[tid] = fmaxf(red[tid], red[tid + st]);
        __syncthreads();
    }
    float M = 10.f * fmaxf(red[0], 0.f);
    __syncthreads();
    float s2 = 0.f, n0 = 0.f;
#pragma unroll
    for (int c = tid; c < 512; c += 256) {
        uint4 u = srow[c];
        unsigned int w[4] = {u.x, u.y, u.z, u.w};
#pragma unroll
        for (int qq = 0; qq < 4; qq++) {
            float v0 = __uint_as_float(w[qq] << 16);
            float v1 = __uint_as_float(w[qq] & 0xFFFF0000u);
            if (v0 >= t) s2 += __expf(10.f * v0 - M); else n0 += 1.f;
            if (v1 >= t) s2 += __expf(10.f * v1 - M); else n0 += 1.f;
        }
    }
    red[tid] = s2; red2[tid] = n0; __syncthreads();
    for (int st = 128; st > 0; st >>= 1) {
        if (tid < st) { red[tid] += red[tid + st]; red2[tid] += red2[tid + st]; }
        __syncthreads();
    }
    float S2 = red[0], N0 = red2[0];
    float iD = 1.f / (S2 + 1e-8f * (S2 + N0 * __expf(-M)));
#pragma unroll
    for (int c = tid; c < 512; c += 256) {
        uint4 u = srow[c];
        unsigned int w[4] = {u.x, u.y, u.z, u.w};
        unsigned int o[4];
#pragma unroll
        for (int qq = 0; qq < 4; qq++) {
            float v0 = __uint_as_float(w[qq] << 16);
            float v1 = __uint_as_float(w[qq] & 0xFFFF0000u);
            float a0 = (v0 >= t) ? __expf(10.f * v0 - M) * iD : 0.f;
            float a1 = (v1 >= t) ? __expf(10.f * v1 - M) * iD : 0.f;
            o[qq] = (unsigned int)f2bf(a0) | ((unsigned int)f2bf(a1) << 16);
        }
        g4[c] = make_uint4(o[0], o[1], o[2], o[3]);
    }
}

// ---- fold (overlap-add gather) + divide by cnt -> zi -----------------------
__global__ void k_fold(const float* __restrict__ agg, float* __restrict__ zi) {
    int p = blockIdx.x * 256 + threadIdx.x;
    int x = p & 255, y = (p >> 8) & 255, ci = (p >> 16) & 15, n = p >> 20;
    int yp = y + 1, xp = x + 1;
    int lh1 = yp >> 2; if (lh1 > 63) lh1 = 63;
    int lh0 = (yp >= 3) ? ((yp - 3) >> 2) : 0;
    int lw1 = xp >> 2; if (lw1 > 63) lw1 = 63;
    int lw0 = (xp >= 3) ? ((xp - 3) >> 2) : 0;
    const float* an = agg + (size_t)n * LL * DINP;
    float sum = 0.f;
    for (int lh = lh0; lh <= lh1; lh++) {
        int dy = yp - 4 * lh;
        for (int lw = lw0; lw <= lw1; lw++) {
            int dx = xp - 4 * lw;
            sum += an[(size_t)(lh * 64 + lw) * DINP + ci * 49 + dy * 7 + dx];
        }
    }
    float cnt = (float)((lh1 - lh0 + 1) * (lw1 - lw0 + 1));
    zi[p] = sum / cnt;
}

// ---- final: out = b + zi @ W_w^T + W_b -------------------------------------
__global__ void k_final(const float* __restrict__ zi, const float* __restrict__ b,
                        const float* __restrict__ W_w, const float* __restrict__ W_b,
                        float* __restrict__ out) {
    __shared__ float w[16 * 64];
    int tid = threadIdx.x;
    for (int i = tid; i < 16 * 64; i += 256) {
        int ci = i >> 6; int co = i & 63;
        w[i] = W_w[co * 16 + ci];
    }
    __syncthreads();
    int p = blockIdx.x * 256 + tid;
    int n = p >> 16, yx = p & 65535;
    float acc[64];
#pragma unroll
    for (int co = 0; co < 64; co++) acc[co] = 0.f;
    const float* zn = zi + (size_t)n * 16 * 65536;
#pragma unroll
    for (int ci = 0; ci < 16; ci++) {
        float v = zn[ci * 65536 + yx];
#pragma unroll
        for (int co = 0; co < 64; co++) acc[co] += v * w[ci * 64 + co];
    }
    const float* bn = b + (size_t)n * 64 * 65536;
    float* on = out + (size_t)n * 64 * 65536;
#pragma unroll
    for (int co = 0; co < 64; co++) on[co * 65536 + yx] = bn[co * 65536 + yx] + acc[co] + W_b[co];
}

extern "C" void kernel_launch(void* const* d_in, const int* in_sizes, int n_in,
                              void* d_out, int out_size, void* d_ws, size_t ws_size,
                              hipStream_t stream) {
    const float* b     = (const float*)d_in[0];
    const float* g_w   = (const float*)d_in[1];
    const float* g_b   = (const float*)d_in[2];
    const float* th_w  = (const float*)d_in[3];
    const float* th_b  = (const float*)d_in[4];
    const float* W_w   = (const float*)d_in[5];
    const float* W_b   = (const float*)d_in[6];
    const float* fc1_w = (const float*)d_in[7];
    const float* fc1_b = (const float*)d_in[8];
    const float* fc2_w = (const float*)d_in[9];
    const float* fc2_b = (const float*)d_in[10];
    const float* thr_w = (const float*)d_in[11];
    const float* thr_b = (const float*)d_in[12];
    // d_in[13], d_in[14] (bias conv): constant along softmax axis -> cancels.
    float* out = (float*)d_out;

    float* ws = (float*)d_ws;
    size_t off = 0;
    auto alloc = [&](size_t nf) { float* p = ws + off; off += (nf + 63) & ~(size_t)63; return p; };
    float* agg  = alloc((size_t)NB * LL * DINP);
    float* zi   = alloc((size_t)NB * CI * HH * WWD);
    unsigned short* bTp  = (unsigned short*)alloc((size_t)NB * YP * 8 * XP * 8 / 2);
    unsigned short* bx   = (unsigned short*)alloc((size_t)NB * HH * WWD * 32 / 2);
    unsigned short* Pb   = (unsigned short*)alloc((size_t)NB * LL * DKP / 2);
    unsigned short* piT  = (unsigned short*)alloc((size_t)NB * DINP * LL / 2);
    unsigned short* fcout = (unsigned short*)alloc((size_t)NB * 2 * LL * DOUTP / 2);
    unsigned short* wbt  = (unsigned short*)alloc(18432 / 2);
    unsigned short* fcwb = (unsigned short*)alloc((size_t)2 * DOUTP * DKP / 2);
    float* thr  = alloc((size_t)NB * LL);
    unsigned short* score = (unsigned short*)alloc((size_t)NB * LL * LL / 2);

    k_prep_b<<<dim3(NB * YP * 8), 256, 0, stream>>>(b, bTp);
    k_prep_wb<<<dim3(72), 256, 0, stream>>>(g_w, th_w, wbt);
    k_prep_fc<<<dim3((2 * DOUTP * DKP + 255) / 256), 256, 0, stream>>>(fc1_w, fc2_w, fcwb);
    k_convm<<<dim3(NB * 256), 256, 0, stream>>>(bTp, wbt, g_b, th_b, bx);
    k_thr<<<dim3(2048), 256, 0, stream>>>(b, thr_w, thr_b, thr);
    k_patchesA<<<dim3((int)((size_t)NB * LL * DKP / 256)), 256, 0, stream>>>(bx, Pb);
    k_patchesT<<<dim3((int)((size_t)NB * DINP * LL / 256)), 256, 0, stream>>>(bx, piT);
    // FC: wif/xif = relu(Pb @ fcwb^T + bias) -> fcout[z=n*2+f][4096][256] bf16
    k_gemm_nt<2><<<dim3(32, 2, 4), 256, 0, stream>>>(
        Pb, fcwb, (void*)fcout, DKP, DKP, DOUTP, DKP,
        (size_t)LL * DKP, (size_t)DOUTP * DKP, (size_t)LL * DOUTP, fc1_b, fc2_b);
    // score[l][m] = wif[l].xif[m]  (bf16 out)
    k_gemm_nt<1><<<dim3(32, 32, NB), 256, 0, stream>>>(
        fcout, fcout + (size_t)LL * DOUTP, (void*)score, DOUTP, DOUTP, LL, DOUTP,
        (size_t)2 * LL * DOUTP, (size_t)2 * LL * DOUTP, (size_t)LL * LL, nullptr, nullptr);
    k_softmax<<<dim3(NB * LL), 256, 0, stream>>>(score, thr);
    // agg[l][d] = sum_m attn[l][m] * piT[d][m]  (fp32 out)
    k_gemm_nt<0><<<dim3(32, DINP / 128, NB), 256, 0, stream>>>(
        score, piT, (void*)agg, LL, LL, DINP, LL,
        (size_t)LL * LL, (size_t)DINP * LL, (size_t)LL * DINP, nullptr, nullptr);
    k_fold<<<dim3(8192), 256, 0, stream>>>(agg, zi);
    k_final<<<dim3(512), 256, 0, stream>>>(zi, b, W_w, W_b, out);
}

// Round 6
// 400.853 us; speedup vs baseline: 4.4948x; 1.0797x over previous
//
#include <hip/hip_runtime.h>
#include <math.h>

#define CIN  64
#define CI   16
#define HH   256
#define WWD  256
#define KS   7
#define STR  4
#define LH   64
#define LWD  64
#define LL   4096
#define DIN  784
#define DINP 896     // padded to multiple of 128 (agg N)
#define DKP  832     // DIN padded to multiple of 64 (fc K)
#define DOUT 196
#define DOUTP 256    // padded N for fc / K for score GEMM
#define NB   2
#define YP   258     // padded rows in bTp
#define XP   264     // padded cols in bTp

typedef __attribute__((ext_vector_type(8))) short bf16x8;
typedef __attribute__((ext_vector_type(4))) float f32x4;

__device__ __forceinline__ unsigned short f2bf(float x) {
    unsigned int u = __float_as_uint(x);
    unsigned int r = (u + 0x7FFFu + ((u >> 16) & 1u)) >> 16;
    return (unsigned short)r;
}
__device__ __forceinline__ float bf2f(unsigned short h) {
    return __uint_as_float(((unsigned int)h) << 16);
}

__device__ __forceinline__ void stage16(const void* g, void* l) {
#if defined(__has_builtin)
#if __has_builtin(__builtin_amdgcn_global_load_lds)
    __builtin_amdgcn_global_load_lds(
        (const __attribute__((address_space(1))) unsigned int*)g,
        (__attribute__((address_space(3))) unsigned int*)l, 16, 0, 0);
    return;
#endif
#endif
    *(float4*)l = *(const float4*)g;
}

// ---- prep: b (fp32 NCHW) -> bTp bf16 [n][y+1][s=ci/8][x+4][j=ci%8], padded -
__global__ __launch_bounds__(256) void k_prep_b(const float* __restrict__ b,
                                                unsigned short* __restrict__ bTp) {
    int blk = blockIdx.x;            // n*YP*8 blocks
    int s = blk & 7; int yy = (blk >> 3) % YP; int n = blk / (8 * YP);
    int y = yy - 1;
    for (int xx = threadIdx.x; xx < XP; xx += 256) {
        int x = xx - 4;
        bool v = (y >= 0 && y < 256 && x >= 0 && x < 256);
        unsigned short h[8];
#pragma unroll
        for (int j = 0; j < 8; j++)
            h[j] = v ? f2bf(b[((size_t)(n * 64 + s * 8 + j) * 256 + y) * 256 + x]) : (unsigned short)0;
        *(uint4*)&bTp[((((size_t)n * YP + yy) * 8 + s) * XP + xx) * 8] = *(uint4*)h;
    }
}

// ---- prep: conv weights -> wbt[t][h][q][co32][j8] bf16 (g: co<16; theta: co>=16, t==4 only)
__global__ void k_prep_wb(const float* __restrict__ g_w, const float* __restrict__ th_w,
                          unsigned short* __restrict__ wbt) {
    int i = blockIdx.x * 256 + threadIdx.x;
    if (i >= 18432) return;
    int j = i & 7, co = (i >> 3) & 31, q = (i >> 8) & 3, h = (i >> 10) & 1, t = i >> 11;
    int ci = h * 32 + q * 8 + j;
    float v;
    if (co < 16) v = g_w[((size_t)co * 64 + ci) * 9 + t];
    else         v = (t == 4) ? th_w[(size_t)(co - 16) * 64 + ci] : 0.f;
    wbt[i] = f2bf(v);
}

// ---- prep: fc weights -> bf16 [f][256][832], zero-padded -------------------
__global__ void k_prep_fc(const float* __restrict__ fc1_w, const float* __restrict__ fc2_w,
                          unsigned short* __restrict__ fcwb) {
    int i = blockIdx.x * 256 + threadIdx.x;
    if (i >= 2 * DOUTP * DKP) return;
    int col = i % DKP; int row = (i / DKP) % DOUTP; int f = i / (DKP * DOUTP);
    float v = 0.f;
    if (row < DOUT && col < DIN) v = (f ? fc2_w : fc1_w)[row * DIN + col];
    fcwb[i] = f2bf(v);
}

// ---- MFMA implicit-GEMM conv: bx[n][y][x][co32] = {g-conv | theta-conv} ----
__global__ __launch_bounds__(256) void k_convm(
        const unsigned short* __restrict__ bTp, const unsigned short* __restrict__ wbt,
        const float* __restrict__ g_b, const float* __restrict__ th_b,
        unsigned short* __restrict__ bx) {
    __shared__ unsigned short wb[18432];       // 36 KB weights
    __shared__ unsigned short ti[8 * 3 * 68 * 8];  // 26 KB input tile [s][r][68 c][8 j]
    int tid = threadIdx.x;
#pragma unroll
    for (int i = 0; i < 9; i++) {              // 2304 chunks of 16B
        int c = i * 256 + tid;
        stage16(wbt + (size_t)c * 8, &wb[c * 8]);
    }
    int n = blockIdx.x >> 8, y = blockIdx.x & 255;
    int wave = tid >> 6, lane = tid & 63, lr = lane & 15, q = lane >> 4;
    int m0 = wave * 16;
    float bg = g_b[lr], bt = th_b[lr];
    for (int xs = 0; xs < 4; xs++) {
        __syncthreads();
        int x0 = xs * 64;
#pragma unroll
        for (int i = 0; i < 7; i++) {          // 1632 chunks of 16B
            int c = i * 256 + tid;
            if (c < 1632) {
                int s = c / 204; int rem = c % 204; int r = rem / 68; int cc = rem % 68;
                const unsigned short* src =
                    bTp + ((((size_t)n * YP + y + r) * 8 + s) * XP + (x0 + 3 + cc)) * 8;
                stage16(src, &ti[c * 8]);
            }
        }
        __syncthreads();
        f32x4 a0 = {bg, bg, bg, bg}, a1 = {bt, bt, bt, bt};
#pragma unroll
        for (int t = 0; t < 9; t++) {
            int dy = t / 3, dx = t % 3;
#pragma unroll
            for (int h = 0; h < 2; h++) {
                int s = h * 4 + q;
                bf16x8 av = *(const bf16x8*)&ti[(((s * 3 + dy) * 68) + m0 + lr + dx) * 8];
                bf16x8 b0 = *(const bf16x8*)&wb[((((t * 2 + h) * 4 + q) * 32) + lr) * 8];
                bf16x8 b1 = *(const bf16x8*)&wb[((((t * 2 + h) * 4 + q) * 32) + 16 + lr) * 8];
                a0 = __builtin_amdgcn_mfma_f32_16x16x32_bf16(av, b0, a0, 0, 0, 0);
                a1 = __builtin_amdgcn_mfma_f32_16x16x32_bf16(av, b1, a1, 0, 0, 0);
            }
        }
        size_t pb = (((size_t)n * 256 + y) * 256 + x0 + m0 + q * 4);
#pragma unroll
        for (int r = 0; r < 4; r++) {
            bx[(pb + r) * 32 + lr]      = f2bf(a0[r]);
            bx[(pb + r) * 32 + 16 + lr] = f2bf(a1[r]);
        }
    }
}

// ---- thr: 7x7 stride-4 conv from bf16 bTp; wave per output, lane=(s,j)=ci --
__global__ __launch_bounds__(256) void k_thr(
        const unsigned short* __restrict__ bTp, const float* __restrict__ thr_w,
        const float* __restrict__ thr_b, float* __restrict__ thr) {
    __shared__ float w[64 * 49];
    int tid = threadIdx.x;
    for (int i = tid; i < 64 * 49; i += 256) w[i] = thr_w[i];
    __syncthreads();
    int wid = (blockIdx.x << 2) + (tid >> 6);
    int lane = tid & 63;
    int s = lane >> 3, j = lane & 7;
    int n = wid >> 12, l = wid & 4095;
    int lh = (l >> 6), lw = l & 63;
    const float* wl = w + (s * 8 + j) * 49;
    float acc = 0.f;
#pragma unroll
    for (int dy = 0; dy < 7; dy++) {
        int yy = lh * 4 + dy;              // y+1; zeros live at yy=0 and yy=257
        if (yy >= YP) continue;            // only lh=63,dy=6 (pure pad) — wave-uniform
        const unsigned short* row = bTp + (((size_t)(n * YP + yy) * 8 + s) * XP) * 8;
#pragma unroll
        for (int dx = 0; dx < 7; dx++) {
            int xx = lw * 4 + dx + 3;      // x+4; pad region holds zeros
            acc = fmaf(bf2f(row[xx * 8 + j]), wl[dy * 7 + dx], acc);
        }
    }
#pragma unroll
    for (int off = 32; off > 0; off >>= 1) acc += __shfl_down(acc, off, 64);
    if (lane == 0) thr[wid] = acc + thr_b[0];
}

// ---- patches of bx(co<16) -> Pb bf16 [n][l][DKP], zero-padded --------------
__global__ void k_patchesA(const unsigned short* __restrict__ bx, unsigned short* __restrict__ Pb) {
    size_t e = (size_t)blockIdx.x * 256 + threadIdx.x;
    if (e >= (size_t)NB * LL * DKP) return;
    int d = (int)(e % DKP); size_t r = e / DKP;
    int l = (int)(r & 4095); int n = (int)(r >> 12);
    unsigned short v = 0;
    if (d < DIN) {
        int ci = d / 49; int t = d % 49; int dy = t / 7; int dx = t % 7;
        int y = (l >> 6) * 4 + dy - 1, x = (l & 63) * 4 + dx - 1;
        if (y >= 0 && y < 256 && x >= 0 && x < 256)
            v = bx[(((size_t)n * 256 + y) * 256 + x) * 32 + ci];
    }
    Pb[e] = v;
}

// ---- patches of bx(co>=16) -> piT bf16 [n][d][l], d padded to DINP ---------
__global__ void k_patchesT(const unsigned short* __restrict__ bx, unsigned short* __restrict__ piT) {
    size_t e = (size_t)blockIdx.x * 256 + threadIdx.x;
    int l = (int)(e & 4095);
    int d = (int)((e >> 12) % DINP);
    int n = (int)(e / ((size_t)DINP * LL));
    unsigned short v = 0;
    if (d < DIN) {
        int ci = d / 49; int t = d % 49; int dy = t / 7; int dx = t % 7;
        int y = (l >> 6) * 4 + dy - 1, x = (l & 63) * 4 + dx - 1;
        if (y >= 0 && y < 256 && x >= 0 && x < 256)
            v = bx[(((size_t)n * 256 + y) * 256 + x) * 32 + 16 + ci];
    }
    piT[e] = v;
}

// ---- MFMA GEMM (NT): C[MxN] = A[MxK] * Bt[NxK]^T ---------------------------
// MODE 0: fp32 out. MODE 1: bf16 out. MODE 2: fc epilogue (bias+relu, bf16).
// MODE 3: K-split (z = batch*2 + ks, A/B offset ks*kso along K), bf16 out.
template<int MODE>
__global__ __launch_bounds__(256) void k_gemm_nt(
        const unsigned short* __restrict__ A, const unsigned short* __restrict__ Bt,
        void* __restrict__ C, int lda, int ldb, int ldc, int K,
        size_t sA, size_t sB, size_t sC, int kso,
        const float* __restrict__ bias1, const float* __restrict__ bias2) {
    __shared__ unsigned short lA[128 * 64];
    __shared__ unsigned short lB[128 * 64];
    int tid = threadIdx.x;
    int wave = tid >> 6, lane = tid & 63;
    int lr = lane & 15, lq = lane >> 4;
    int wm = (wave >> 1) * 64, wn = (wave & 1) * 64;
    int i0 = blockIdx.x * 128, j0 = blockIdx.y * 128;
    int z = blockIdx.z;
    int az = (MODE == 2 || MODE == 3) ? (z >> 1) : z;
    int bz = (MODE == 2) ? (z & 1) : az;
    size_t koff = (MODE == 3) ? (size_t)(z & 1) * kso : 0;
    const unsigned short* Ab = A + (size_t)az * sA + koff + (size_t)i0 * lda;
    const unsigned short* Bb = Bt + (size_t)bz * sB + koff + (size_t)j0 * ldb;
    f32x4 acc[4][4] = {};
    for (int k0 = 0; k0 < K; k0 += 64) {
        __syncthreads();
#pragma unroll
        for (int it = 0; it < 4; it++) {
            int c = it * 256 + tid;
            int row = c >> 3, slot = c & 7;
            int col8 = slot ^ (row & 7);
            stage16(Ab + (size_t)row * lda + k0 + col8 * 8, &lA[c * 8]);
        }
#pragma unroll
        for (int it = 0; it < 4; it++) {
            int c = it * 256 + tid;
            int row = c >> 3, slot = c & 7;
            int col8 = slot ^ (row & 7);
            stage16(Bb + (size_t)row * ldb + k0 + col8 * 8, &lB[c * 8]);
        }
        __syncthreads();
#pragma unroll
        for (int ks = 0; ks < 2; ks++) {
            bf16x8 af[4], bfr[4];
#pragma unroll
            for (int t = 0; t < 4; t++) {
                int row = wm + t * 16 + lr;
                int slot = ks * 4 + lq;
                af[t] = *(const bf16x8*)&lA[row * 64 + (slot ^ (row & 7)) * 8];
            }
#pragma unroll
            for (int t = 0; t < 4; t++) {
                int row = wn + t * 16 + lr;
                int slot = ks * 4 + lq;
                bfr[t] = *(const bf16x8*)&lB[row * 64 + (slot ^ (row & 7)) * 8];
            }
#pragma unroll
            for (int mi = 0; mi < 4; mi++)
#pragma unroll
                for (int nj = 0; nj < 4; nj++)
                    acc[mi][nj] = __builtin_amdgcn_mfma_f32_16x16x32_bf16(
                        af[mi], bfr[nj], acc[mi][nj], 0, 0, 0);
        }
    }
    if (MODE == 0) {
        float* Cf = (float*)C + (size_t)z * sC;
#pragma unroll
        for (int mi = 0; mi < 4; mi++)
#pragma unroll
            for (int r = 0; r < 4; r++) {
                int row = i0 + wm + mi * 16 + lq * 4 + r;
#pragma unroll
                for (int nj = 0; nj < 4; nj++)
                    Cf[(size_t)row * ldc + j0 + wn + nj * 16 + lr] = acc[mi][nj][r];
            }
    } else if (MODE == 1 || MODE == 3) {
        unsigned short* Cb = (unsigned short*)C + (size_t)z * sC;
#pragma unroll
        for (int mi = 0; mi < 4; mi++)
#pragma unroll
            for (int r = 0; r < 4; r++) {
                int row = i0 + wm + mi * 16 + lq * 4 + r;
#pragma unroll
                for (int nj = 0; nj < 4; nj++)
                    Cb[(size_t)row * ldc + j0 + wn + nj * 16 + lr] = f2bf(acc[mi][nj][r]);
            }
    } else {
        const float* biasp = bz ? bias2 : bias1;
        unsigned short* Cb = (unsigned short*)C + (size_t)z * sC;
#pragma unroll
        for (int mi = 0; mi < 4; mi++)
#pragma unroll
            for (int r = 0; r < 4; r++) {
                int row = i0 + wm + mi * 16 + lq * 4 + r;
#pragma unroll
                for (int nj = 0; nj < 4; nj++) {
                    int col = j0 + wn + nj * 16 + lr;
                    float bv = (col < DOUT) ? biasp[col] : 0.f;
                    float v = fmaxf(acc[mi][nj][r] + bv, 0.f);
                    Cb[(size_t)row * ldc + col] = f2bf(v);
                }
            }
    }
}

// ---- fused masked-softmax over one score row (stats + transform) -----------
__global__ __launch_bounds__(256) void k_softmax(
        unsigned short* __restrict__ score, const float* __restrict__ thr) {
    __shared__ uint4 srow[512];             // 4096 bf16
    __shared__ float red[256], red2[256];
    int row = blockIdx.x, tid = threadIdx.x;
    uint4* g4 = (uint4*)(score + (size_t)row * LL);
    float t = thr[row];
    float mx = 0.f;
#pragma unroll
    for (int c = tid; c < 512; c += 256) {
        uint4 u = g4[c];
        srow[c] = u;
        unsigned int w[4] = {u.x, u.y, u.z, u.w};
#pragma unroll
        for (int qq = 0; qq < 4; qq++) {
            float v0 = __uint_as_float(w[qq] << 16);
            float v1 = __uint_as_float(w[qq] & 0xFFFF0000u);
            if (v0 >= t) mx = fmaxf(mx, v0);
            if (v1 >= t) mx = fmaxf(mx, v1);
        }
    }
    red[tid] = mx; __syncthreads();
    for (int st = 128; st > 0; st >>= 1) {
        if (tid < st) red[tid] = fmaxf(red[tid], red[tid + st]);
        __syncthreads();
    }
    float M = 10.f * fmaxf(red[0], 0.f);
    __syncthreads();
    float s2 = 0.f, n0 = 0.f;
#pragma unroll
    for (int c = tid; c < 512; c += 256) {
        uint4 u = srow[c];
        unsigned int w[4] = {u.x, u.y, u.z, u.w};
#pragma unroll
        for (int qq = 0; qq < 4; qq++) {
            float v0 = __uint_as_float(w[qq] << 16);
            float v1 = __uint_as_float(w[qq] & 0xFFFF0000u);
            if (v0 >= t) s2 += __expf(10.f * v0 - M); else n0 += 1.f;
            if (v1 >= t) s2 += __expf(10.f * v1 - M); else n0 += 1.f;
        }
    }
    red[tid] = s2; red2[tid] = n0; __syncthreads();
    for (int st = 128; st > 0; st >>= 1) {
        if (tid < st) { red[tid] += red[tid + st]; red2[tid] += red2[tid + st]; }
        __syncthreads();
    }
    float S2 = red[0], N0 = red2[0];
    float iD = 1.f / (S2 + 1e-8f * (S2 + N0 * __expf(-M)));
#pragma unroll
    for (int c = tid; c < 512; c += 256) {
        uint4 u = srow[c];
        unsigned int w[4] = {u.x, u.y, u.z, u.w};
        unsigned int o[4];
#pragma unroll
        for (int qq = 0; qq < 4; qq++) {
            float v0 = __uint_as_float(w[qq] << 16);
            float v1 = __uint_as_float(w[qq] & 0xFFFF0000u);
            float a0 = (v0 >= t) ? __expf(10.f * v0 - M) * iD : 0.f;
            float a1 = (v1 >= t) ? __expf(10.f * v1 - M) * iD : 0.f;
            o[qq] = (unsigned int)f2bf(a0) | ((unsigned int)f2bf(a1) << 16);
        }
        g4[c] = make_uint4(o[0], o[1], o[2], o[3]);
    }
}

// ---- fold: sum 2 bf16 K-split partials, overlap-add gather, /cnt -> zi -----
__global__ void k_fold(const unsigned short* __restrict__ aggb, float* __restrict__ zi) {
    int p = blockIdx.x * 256 + threadIdx.x;
    int x = p & 255, y = (p >> 8) & 255, ci = (p >> 16) & 15, n = p >> 20;
    int yp = y + 1, xp = x + 1;
    int lh1 = yp >> 2; if (lh1 > 63) lh1 = 63;
    int lh0 = (yp >= 3) ? ((yp - 3) >> 2) : 0;
    int lw1 = xp >> 2; if (lw1 > 63) lw1 = 63;
    int lw0 = (xp >= 3) ? ((xp - 3) >> 2) : 0;
    const unsigned short* a0 = aggb + (size_t)(n * 2) * LL * DINP;
    const unsigned short* a1 = a0 + (size_t)LL * DINP;
    float sum = 0.f;
    for (int lh = lh0; lh <= lh1; lh++) {
        int dy = yp - 4 * lh;
        for (int lw = lw0; lw <= lw1; lw++) {
            int dx = xp - 4 * lw;
            size_t idx = (size_t)(lh * 64 + lw) * DINP + ci * 49 + dy * 7 + dx;
            sum += bf2f(a0[idx]) + bf2f(a1[idx]);
        }
    }
    float cnt = (float)((lh1 - lh0 + 1) * (lw1 - lw0 + 1));
    zi[p] = sum / cnt;
}

// ---- final: out = b + zi @ W_w^T + W_b -------------------------------------
__global__ void k_final(const float* __restrict__ zi, const float* __restrict__ b,
                        const float* __restrict__ W_w, const float* __restrict__ W_b,
                        float* __restrict__ out) {
    __shared__ float w[16 * 64];
    int tid = threadIdx.x;
    for (int i = tid; i < 16 * 64; i += 256) {
        int ci = i >> 6; int co = i & 63;
        w[i] = W_w[co * 16 + ci];
    }
    __syncthreads();
    int p = blockIdx.x * 256 + tid;
    int n = p >> 16, yx = p & 65535;
    float acc[64];
#pragma unroll
    for (int co = 0; co < 64; co++) acc[co] = 0.f;
    const float* zn = zi + (size_t)n * 16 * 65536;
#pragma unroll
    for (int ci = 0; ci < 16; ci++) {
        float v = zn[ci * 65536 + yx];
#pragma unroll
        for (int co = 0; co < 64; co++) acc[co] += v * w[ci * 64 + co];
    }
    const float* bn = b + (size_t)n * 64 * 65536;
    float* on = out + (size_t)n * 64 * 65536;
#pragma unroll
    for (int co = 0; co < 64; co++) on[co * 65536 + yx] = bn[co * 65536 + yx] + acc[co] + W_b[co];
}

extern "C" void kernel_launch(void* const* d_in, const int* in_sizes, int n_in,
                              void* d_out, int out_size, void* d_ws, size_t ws_size,
                              hipStream_t stream) {
    const float* b     = (const float*)d_in[0];
    const float* g_w   = (const float*)d_in[1];
    const float* g_b   = (const float*)d_in[2];
    const float* th_w  = (const float*)d_in[3];
    const float* th_b  = (const float*)d_in[4];
    const float* W_w   = (const float*)d_in[5];
    const float* W_b   = (const float*)d_in[6];
    const float* fc1_w = (const float*)d_in[7];
    const float* fc1_b = (const float*)d_in[8];
    const float* fc2_w = (const float*)d_in[9];
    const float* fc2_b = (const float*)d_in[10];
    const float* thr_w = (const float*)d_in[11];
    const float* thr_b = (const float*)d_in[12];
    // d_in[13], d_in[14] (bias conv): constant along softmax axis -> cancels.
    float* out = (float*)d_out;

    float* ws = (float*)d_ws;
    size_t off = 0;
    auto alloc = [&](size_t nf) { float* p = ws + off; off += (nf + 63) & ~(size_t)63; return p; };
    unsigned short* aggb = (unsigned short*)alloc((size_t)2 * NB * LL * DINP / 2);  // 2 K-split bf16 partials
    float* zi   = alloc((size_t)NB * CI * HH * WWD);
    unsigned short* bTp  = (unsigned short*)alloc((size_t)NB * YP * 8 * XP * 8 / 2);
    unsigned short* bx   = (unsigned short*)alloc((size_t)NB * HH * WWD * 32 / 2);
    unsigned short* Pb   = (unsigned short*)alloc((size_t)NB * LL * DKP / 2);
    unsigned short* piT  = (unsigned short*)alloc((size_t)NB * DINP * LL / 2);
    unsigned short* fcout = (unsigned short*)alloc((size_t)NB * 2 * LL * DOUTP / 2);
    unsigned short* wbt  = (unsigned short*)alloc(18432 / 2);
    unsigned short* fcwb = (unsigned short*)alloc((size_t)2 * DOUTP * DKP / 2);
    float* thr  = alloc((size_t)NB * LL);
    unsigned short* score = (unsigned short*)alloc((size_t)NB * LL * LL / 2);

    k_prep_b<<<dim3(NB * YP * 8), 256, 0, stream>>>(b, bTp);
    k_prep_wb<<<dim3(72), 256, 0, stream>>>(g_w, th_w, wbt);
    k_prep_fc<<<dim3((2 * DOUTP * DKP + 255) / 256), 256, 0, stream>>>(fc1_w, fc2_w, fcwb);
    k_convm<<<dim3(NB * 256), 256, 0, stream>>>(bTp, wbt, g_b, th_b, bx);
    k_thr<<<dim3(2048), 256, 0, stream>>>(bTp, thr_w, thr_b, thr);
    k_patchesA<<<dim3((int)((size_t)NB * LL * DKP / 256)), 256, 0, stream>>>(bx, Pb);
    k_patchesT<<<dim3((int)((size_t)NB * DINP * LL / 256)), 256, 0, stream>>>(bx, piT);
    // FC: wif/xif = relu(Pb @ fcwb^T + bias) -> fcout[z=n*2+f][4096][256] bf16
    k_gemm_nt<2><<<dim3(32, 2, 4), 256, 0, stream>>>(
        Pb, fcwb, (void*)fcout, DKP, DKP, DOUTP, DKP,
        (size_t)LL * DKP, (size_t)DOUTP * DKP, (size_t)LL * DOUTP, 0, fc1_b, fc2_b);
    // score[l][m] = wif[l].xif[m]  (bf16 out)
    k_gemm_nt<1><<<dim3(32, 32, NB), 256, 0, stream>>>(
        fcout, fcout + (size_t)LL * DOUTP, (void*)score, DOUTP, DOUTP, LL, DOUTP,
        (size_t)2 * LL * DOUTP, (size_t)2 * LL * DOUTP, (size_t)LL * LL, 0, nullptr, nullptr);
    k_softmax<<<dim3(NB * LL), 256, 0, stream>>>(score, thr);
    // agg partials: z = n*2+ks, K=2048 each, bf16 out [z][4096][896]
    k_gemm_nt<3><<<dim3(32, DINP / 128, NB * 2), 256, 0, stream>>>(
        score, piT, (void*)aggb, LL, LL, DINP, LL / 2,
        (size_t)LL * LL, (size_t)DINP * LL, (size_t)LL * DINP, LL / 2, nullptr, nullptr);
    k_fold<<<dim3(8192), 256, 0, stream>>>(aggb, zi);
    k_final<<<dim3(512), 256, 0, stream>>>(zi, b, W_w, W_b, out);
}

// Round 7
// 330.845 us; speedup vs baseline: 5.4459x; 1.2116x over previous
//
#include <hip/hip_runtime.h>
#include <math.h>

#define CIN  64
#define CI   16
#define HH   256
#define WWD  256
#define KS   7
#define STR  4
#define LH   64
#define LWD  64
#define LL   4096
#define DIN  784
#define DINP 896     // padded to multiple of 128 (agg N)
#define DKP  832     // DIN padded to multiple of 64 (fc K)
#define DOUT 196
#define DOUTP 256    // padded N for fc / K for score GEMM
#define NB   2
#define YP   258     // padded rows in bTp
#define XP   264     // padded cols in bTp

typedef __attribute__((ext_vector_type(8))) short bf16x8;
typedef __attribute__((ext_vector_type(4))) float f32x4;
typedef __attribute__((ext_vector_type(16))) float f32x16;
typedef __attribute__((ext_vector_type(8))) int i32x8;
typedef __attribute__((ext_vector_type(4))) int i32x4;

__device__ __forceinline__ unsigned short f2bf(float x) {
    unsigned int u = __float_as_uint(x);
    unsigned int r = (u + 0x7FFFu + ((u >> 16) & 1u)) >> 16;
    return (unsigned short)r;
}
__device__ __forceinline__ float bf2f(unsigned short h) {
    return __uint_as_float(((unsigned int)h) << 16);
}

__device__ __forceinline__ void stage16(const void* g, void* l) {
#if defined(__has_builtin)
#if __has_builtin(__builtin_amdgcn_global_load_lds)
    __builtin_amdgcn_global_load_lds(
        (const __attribute__((address_space(1))) unsigned int*)g,
        (__attribute__((address_space(3))) unsigned int*)l, 16, 0, 0);
    return;
#endif
#endif
    *(float4*)l = *(const float4*)g;
}

// ---- prep: b (fp32 NCHW) -> bTp bf16 [n][y+1][s=ci/8][x+4][j=ci%8], padded -
__global__ __launch_bounds__(256) void k_prep_b(const float* __restrict__ b,
                                                unsigned short* __restrict__ bTp) {
    int blk = blockIdx.x;            // n*YP*8 blocks
    int s = blk & 7; int yy = (blk >> 3) % YP; int n = blk / (8 * YP);
    int y = yy - 1;
    for (int xx = threadIdx.x; xx < XP; xx += 256) {
        int x = xx - 4;
        bool v = (y >= 0 && y < 256 && x >= 0 && x < 256);
        unsigned short h[8];
#pragma unroll
        for (int j = 0; j < 8; j++)
            h[j] = v ? f2bf(b[((size_t)(n * 64 + s * 8 + j) * 256 + y) * 256 + x]) : (unsigned short)0;
        *(uint4*)&bTp[((((size_t)n * YP + yy) * 8 + s) * XP + xx) * 8] = *(uint4*)h;
    }
}

// ---- prep: conv weights -> wbt[t][h][q][co32][j8] bf16 ---------------------
__global__ void k_prep_wb(const float* __restrict__ g_w, const float* __restrict__ th_w,
                          unsigned short* __restrict__ wbt) {
    int i = blockIdx.x * 256 + threadIdx.x;
    if (i >= 18432) return;
    int j = i & 7, co = (i >> 3) & 31, q = (i >> 8) & 3, h = (i >> 10) & 1, t = i >> 11;
    int ci = h * 32 + q * 8 + j;
    float v;
    if (co < 16) v = g_w[((size_t)co * 64 + ci) * 9 + t];
    else         v = (t == 4) ? th_w[(size_t)(co - 16) * 64 + ci] : 0.f;
    wbt[i] = f2bf(v);
}

// ---- prep: fc weights -> bf16 [f][256][832], zero-padded -------------------
__global__ void k_prep_fc(const float* __restrict__ fc1_w, const float* __restrict__ fc2_w,
                          unsigned short* __restrict__ fcwb) {
    int i = blockIdx.x * 256 + threadIdx.x;
    if (i >= 2 * DOUTP * DKP) return;
    int col = i % DKP; int row = (i / DKP) % DOUTP; int f = i / (DKP * DOUTP);
    float v = 0.f;
    if (row < DOUT && col < DIN) v = (f ? fc2_w : fc1_w)[row * DIN + col];
    fcwb[i] = f2bf(v);
}

// ---- MFMA implicit-GEMM conv: bx[n][y][x][co32] ----------------------------
__global__ __launch_bounds__(256) void k_convm(
        const unsigned short* __restrict__ bTp, const unsigned short* __restrict__ wbt,
        const float* __restrict__ g_b, const float* __restrict__ th_b,
        unsigned short* __restrict__ bx) {
    __shared__ unsigned short wb[18432];
    __shared__ unsigned short ti[8 * 3 * 68 * 8];
    int tid = threadIdx.x;
#pragma unroll
    for (int i = 0; i < 9; i++) {
        int c = i * 256 + tid;
        stage16(wbt + (size_t)c * 8, &wb[c * 8]);
    }
    int n = blockIdx.x >> 8, y = blockIdx.x & 255;
    int wave = tid >> 6, lane = tid & 63, lr = lane & 15, q = lane >> 4;
    int m0 = wave * 16;
    float bg = g_b[lr], bt = th_b[lr];
    for (int xs = 0; xs < 4; xs++) {
        __syncthreads();
        int x0 = xs * 64;
#pragma unroll
        for (int i = 0; i < 7; i++) {
            int c = i * 256 + tid;
            if (c < 1632) {
                int s = c / 204; int rem = c % 204; int r = rem / 68; int cc = rem % 68;
                const unsigned short* src =
                    bTp + ((((size_t)n * YP + y + r) * 8 + s) * XP + (x0 + 3 + cc)) * 8;
                stage16(src, &ti[c * 8]);
            }
        }
        __syncthreads();
        f32x4 a0 = {bg, bg, bg, bg}, a1 = {bt, bt, bt, bt};
#pragma unroll
        for (int t = 0; t < 9; t++) {
            int dy = t / 3, dx = t % 3;
#pragma unroll
            for (int h = 0; h < 2; h++) {
                int s = h * 4 + q;
                bf16x8 av = *(const bf16x8*)&ti[(((s * 3 + dy) * 68) + m0 + lr + dx) * 8];
                bf16x8 b0 = *(const bf16x8*)&wb[((((t * 2 + h) * 4 + q) * 32) + lr) * 8];
                bf16x8 b1 = *(const bf16x8*)&wb[((((t * 2 + h) * 4 + q) * 32) + 16 + lr) * 8];
                a0 = __builtin_amdgcn_mfma_f32_16x16x32_bf16(av, b0, a0, 0, 0, 0);
                a1 = __builtin_amdgcn_mfma_f32_16x16x32_bf16(av, b1, a1, 0, 0, 0);
            }
        }
        size_t pb = (((size_t)n * 256 + y) * 256 + x0 + m0 + q * 4);
#pragma unroll
        for (int r = 0; r < 4; r++) {
            bx[(pb + r) * 32 + lr]      = f2bf(a0[r]);
            bx[(pb + r) * 32 + 16 + lr] = f2bf(a1[r]);
        }
    }
}

// ---- thr: 7x7 stride-4 conv from bf16 bTp; wave per output, lane=(s,j)=ci --
__global__ __launch_bounds__(256) void k_thr(
        const unsigned short* __restrict__ bTp, const float* __restrict__ thr_w,
        const float* __restrict__ thr_b, float* __restrict__ thr) {
    __shared__ float w[64 * 49];
    int tid = threadIdx.x;
    for (int i = tid; i < 64 * 49; i += 256) w[i] = thr_w[i];
    __syncthreads();
    int wid = (blockIdx.x << 2) + (tid >> 6);
    int lane = tid & 63;
    int s = lane >> 3, j = lane & 7;
    int n = wid >> 12, l = wid & 4095;
    int lh = (l >> 6), lw = l & 63;
    const float* wl = w + (s * 8 + j) * 49;
    float acc = 0.f;
#pragma unroll
    for (int dy = 0; dy < 7; dy++) {
        int yy = lh * 4 + dy;
        if (yy >= YP) continue;
        const unsigned short* row = bTp + (((size_t)(n * YP + yy) * 8 + s) * XP) * 8;
#pragma unroll
        for (int dx = 0; dx < 7; dx++) {
            int xx = lw * 4 + dx + 3;
            acc = fmaf(bf2f(row[xx * 8 + j]), wl[dy * 7 + dx], acc);
        }
    }
#pragma unroll
    for (int off = 32; off > 0; off >>= 1) acc += __shfl_down(acc, off, 64);
    if (lane == 0) thr[wid] = acc + thr_b[0];
}

// ---- patches of bx(co<16) -> Pb bf16 [n][l][DKP], zero-padded --------------
__global__ void k_patchesA(const unsigned short* __restrict__ bx, unsigned short* __restrict__ Pb) {
    size_t e = (size_t)blockIdx.x * 256 + threadIdx.x;
    if (e >= (size_t)NB * LL * DKP) return;
    int d = (int)(e % DKP); size_t r = e / DKP;
    int l = (int)(r & 4095); int n = (int)(r >> 12);
    unsigned short v = 0;
    if (d < DIN) {
        int ci = d / 49; int t = d % 49; int dy = t / 7; int dx = t % 7;
        int y = (l >> 6) * 4 + dy - 1, x = (l & 63) * 4 + dx - 1;
        if (y >= 0 && y < 256 && x >= 0 && x < 256)
            v = bx[(((size_t)n * 256 + y) * 256 + x) * 32 + ci];
    }
    Pb[e] = v;
}

// ---- patches of bx(co>=16) -> piT8 fp8 e4m3 [n][d][l], d padded to DINP ----
__global__ void k_patchesT(const unsigned short* __restrict__ bx, unsigned char* __restrict__ piT8) {
    size_t e = (size_t)blockIdx.x * 256 + threadIdx.x;
    int l = (int)(e & 4095);
    int d = (int)((e >> 12) % DINP);
    int n = (int)(e / ((size_t)DINP * LL));
    float v = 0.f;
    if (d < DIN) {
        int ci = d / 49; int t = d % 49; int dy = t / 7; int dx = t % 7;
        int y = (l >> 6) * 4 + dy - 1, x = (l & 63) * 4 + dx - 1;
        if (y >= 0 && y < 256 && x >= 0 && x < 256)
            v = bf2f(bx[(((size_t)n * 256 + y) * 256 + x) * 32 + 16 + ci]);
    }
    int p = __builtin_amdgcn_cvt_pk_fp8_f32(v, 0.f, 0, false);
    piT8[e] = (unsigned char)(p & 0xFF);
}

// ---- MFMA GEMM (NT) bf16: MODE 1 bf16 out; MODE 2 fc epilogue --------------
template<int MODE>
__global__ __launch_bounds__(256) void k_gemm_nt(
        const unsigned short* __restrict__ A, const unsigned short* __restrict__ Bt,
        void* __restrict__ C, int lda, int ldb, int ldc, int K,
        size_t sA, size_t sB, size_t sC,
        const float* __restrict__ bias1, const float* __restrict__ bias2) {
    __shared__ unsigned short lA[128 * 64];
    __shared__ unsigned short lB[128 * 64];
    int tid = threadIdx.x;
    int wave = tid >> 6, lane = tid & 63;
    int lr = lane & 15, lq = lane >> 4;
    int wm = (wave >> 1) * 64, wn = (wave & 1) * 64;
    int i0 = blockIdx.x * 128, j0 = blockIdx.y * 128;
    int z = blockIdx.z;
    int az = (MODE == 2) ? (z >> 1) : z;
    int bz = (MODE == 2) ? (z & 1) : z;
    const unsigned short* Ab = A + (size_t)az * sA + (size_t)i0 * lda;
    const unsigned short* Bb = Bt + (size_t)bz * sB + (size_t)j0 * ldb;
    f32x4 acc[4][4] = {};
    for (int k0 = 0; k0 < K; k0 += 64) {
        __syncthreads();
#pragma unroll
        for (int it = 0; it < 4; it++) {
            int c = it * 256 + tid;
            int row = c >> 3, slot = c & 7;
            int col8 = slot ^ (row & 7);
            stage16(Ab + (size_t)row * lda + k0 + col8 * 8, &lA[c * 8]);
        }
#pragma unroll
        for (int it = 0; it < 4; it++) {
            int c = it * 256 + tid;
            int row = c >> 3, slot = c & 7;
            int col8 = slot ^ (row & 7);
            stage16(Bb + (size_t)row * ldb + k0 + col8 * 8, &lB[c * 8]);
        }
        __syncthreads();
#pragma unroll
        for (int ks = 0; ks < 2; ks++) {
            bf16x8 af[4], bfr[4];
#pragma unroll
            for (int t = 0; t < 4; t++) {
                int row = wm + t * 16 + lr;
                int slot = ks * 4 + lq;
                af[t] = *(const bf16x8*)&lA[row * 64 + (slot ^ (row & 7)) * 8];
            }
#pragma unroll
            for (int t = 0; t < 4; t++) {
                int row = wn + t * 16 + lr;
                int slot = ks * 4 + lq;
                bfr[t] = *(const bf16x8*)&lB[row * 64 + (slot ^ (row & 7)) * 8];
            }
#pragma unroll
            for (int mi = 0; mi < 4; mi++)
#pragma unroll
                for (int nj = 0; nj < 4; nj++)
                    acc[mi][nj] = __builtin_amdgcn_mfma_f32_16x16x32_bf16(
                        af[mi], bfr[nj], acc[mi][nj], 0, 0, 0);
        }
    }
    if (MODE == 1) {
        unsigned short* Cb = (unsigned short*)C + (size_t)z * sC;
#pragma unroll
        for (int mi = 0; mi < 4; mi++)
#pragma unroll
            for (int r = 0; r < 4; r++) {
                int row = i0 + wm + mi * 16 + lq * 4 + r;
#pragma unroll
                for (int nj = 0; nj < 4; nj++)
                    Cb[(size_t)row * ldc + j0 + wn + nj * 16 + lr] = f2bf(acc[mi][nj][r]);
            }
    } else {
        const float* biasp = bz ? bias2 : bias1;
        unsigned short* Cb = (unsigned short*)C + (size_t)z * sC;
#pragma unroll
        for (int mi = 0; mi < 4; mi++)
#pragma unroll
            for (int r = 0; r < 4; r++) {
                int row = i0 + wm + mi * 16 + lq * 4 + r;
#pragma unroll
                for (int nj = 0; nj < 4; nj++) {
                    int col = j0 + wn + nj * 16 + lr;
                    float bv = (col < DOUT) ? biasp[col] : 0.f;
                    float v = fmaxf(acc[mi][nj][r] + bv, 0.f);
                    Cb[(size_t)row * ldc + col] = f2bf(v);
                }
            }
    }
}

// ---- MX-fp8 MFMA GEMM (NT): agg = attn8 @ piT8^T, unit scales --------------
// 128x128 tile, BK=128 bytes, 4 waves 2x2, wave=64x64 as 2x2 of 32x32x64.
__global__ __launch_bounds__(256) void k_gemm_mx(
        const unsigned char* __restrict__ A, const unsigned char* __restrict__ Bt,
        unsigned short* __restrict__ C, int lda, int ldb, int ldc, int K,
        size_t sA, size_t sB, size_t sC) {
    __shared__ unsigned char lA[128 * 128];
    __shared__ unsigned char lB[128 * 128];
    int tid = threadIdx.x;
    int wave = tid >> 6, lane = tid & 63;
    int lr = lane & 31, hf = lane >> 5;
    int wm = (wave >> 1) * 64, wn = (wave & 1) * 64;
    int i0 = blockIdx.x * 128, j0 = blockIdx.y * 128;
    int z = blockIdx.z;
    const unsigned char* Ab = A + (size_t)z * sA + (size_t)i0 * lda;
    const unsigned char* Bb = Bt + (size_t)z * sB + (size_t)j0 * ldb;
    f32x16 acc[2][2] = {};
    for (int k0 = 0; k0 < K; k0 += 128) {
        __syncthreads();
#pragma unroll
        for (int it = 0; it < 4; it++) {          // A: 1024 chunks of 16B
            int c = it * 256 + tid;
            int row = c >> 3, slot = c & 7;
            int col16 = slot ^ (row & 7);
            stage16(Ab + (size_t)row * lda + k0 + col16 * 16, &lA[c * 16]);
        }
#pragma unroll
        for (int it = 0; it < 4; it++) {          // B: 1024 chunks of 16B
            int c = it * 256 + tid;
            int row = c >> 3, slot = c & 7;
            int col16 = slot ^ (row & 7);
            stage16(Bb + (size_t)row * ldb + k0 + col16 * 16, &lB[c * 16]);
        }
        __syncthreads();
#pragma unroll
        for (int kk = 0; kk < 2; kk++) {          // two K=64 steps
            i32x8 af[2], bfv[2];
            int c0 = kk * 4 + hf * 2;
#pragma unroll
            for (int t = 0; t < 2; t++) {
                int row = wm + t * 32 + lr;
                i32x4 lo = *(const i32x4*)&lA[row * 128 + ((c0    ) ^ (row & 7)) * 16];
                i32x4 hi = *(const i32x4*)&lA[row * 128 + ((c0 + 1) ^ (row & 7)) * 16];
                af[t][0] = lo[0]; af[t][1] = lo[1]; af[t][2] = lo[2]; af[t][3] = lo[3];
                af[t][4] = hi[0]; af[t][5] = hi[1]; af[t][6] = hi[2]; af[t][7] = hi[3];
            }
#pragma unroll
            for (int t = 0; t < 2; t++) {
                int row = wn + t * 32 + lr;
                i32x4 lo = *(const i32x4*)&lB[row * 128 + ((c0    ) ^ (row & 7)) * 16];
                i32x4 hi = *(const i32x4*)&lB[row * 128 + ((c0 + 1) ^ (row & 7)) * 16];
                bfv[t][0] = lo[0]; bfv[t][1] = lo[1]; bfv[t][2] = lo[2]; bfv[t][3] = lo[3];
                bfv[t][4] = hi[0]; bfv[t][5] = hi[1]; bfv[t][6] = hi[2]; bfv[t][7] = hi[3];
            }
#pragma unroll
            for (int mi = 0; mi < 2; mi++)
#pragma unroll
                for (int nj = 0; nj < 2; nj++)
                    acc[mi][nj] = __builtin_amdgcn_mfma_scale_f32_32x32x64_f8f6f4(
                        af[mi], bfv[nj], acc[mi][nj],
                        0, 0,                      // cbsz = fp8(e4m3), blgp = fp8(e4m3)
                        0, 0x7F7F7F7F,             // opsel_a, scale_a = 1.0
                        0, 0x7F7F7F7F);            // opsel_b, scale_b = 1.0
        }
    }
    unsigned short* Cb = C + (size_t)z * sC;
#pragma unroll
    for (int mi = 0; mi < 2; mi++)
#pragma unroll
        for (int nj = 0; nj < 2; nj++)
#pragma unroll
            for (int reg = 0; reg < 16; reg++) {
                int row = i0 + wm + mi * 32 + (reg & 3) + 8 * (reg >> 2) + 4 * hf;
                int col = j0 + wn + nj * 32 + lr;
                Cb[(size_t)row * ldc + col] = f2bf(acc[mi][nj][reg]);
            }
}

// ---- fused masked-softmax: bf16 score row -> fp8 attn row ------------------
__global__ __launch_bounds__(256) void k_softmax(
        const unsigned short* __restrict__ score, const float* __restrict__ thr,
        unsigned char* __restrict__ attn8) {
    __shared__ uint4 srow[512];             // 4096 bf16
    __shared__ float red[256], red2[256];
    int row = blockIdx.x, tid = threadIdx.x;
    const uint4* g4 = (const uint4*)(score + (size_t)row * LL);
    float t = thr[row];
    float mx = 0.f;
#pragma unroll
    for (int c = tid; c < 512; c += 256) {
        uint4 u = g4[c];
        srow[c] = u;
        unsigned int w[4] = {u.x, u.y, u.z, u.w};
#pragma unroll
        for (int qq = 0; qq < 4; qq++) {
            float v0 = __uint_as_float(w[qq] << 16);
            float v1 = __uint_as_float(w[qq] & 0xFFFF0000u);
            if (v0 >= t) mx = fmaxf(mx, v0);
            if (v1 >= t) mx = fmaxf(mx, v1);
        }
    }
    red[tid] = mx; __syncthreads();
    for (int st = 128; st > 0; st >>= 1) {
        if (tid < st) red[tid] = fmaxf(red[tid], red[tid + st]);
        __syncthreads();
    }
    float M = 10.f * fmaxf(red[0], 0.f);
    __syncthreads();
    float s2 = 0.f, n0 = 0.f;
#pragma unroll
    for (int c = tid; c < 512; c += 256) {
        uint4 u = srow[c];
        unsigned int w[4] = {u.x, u.y, u.z, u.w};
#pragma unroll
        for (int qq = 0; qq < 4; qq++) {
            float v0 = __uint_as_float(w[qq] << 16);
            float v1 = __uint_as_float(w[qq] & 0xFFFF0000u);
            if (v0 >= t) s2 += __expf(10.f * v0 - M); else n0 += 1.f;
            if (v1 >= t) s2 += __expf(10.f * v1 - M); else n0 += 1.f;
        }
    }
    red[tid] = s2; red2[tid] = n0; __syncthreads();
    for (int st = 128; st > 0; st >>= 1) {
        if (tid < st) { red[tid] += red[tid + st]; red2[tid] += red2[tid + st]; }
        __syncthreads();
    }
    float S2 = red[0], N0 = red2[0];
    float iD = 1.f / (S2 + 1e-8f * (S2 + N0 * __expf(-M)));
#pragma unroll
    for (int c = tid; c < 512; c += 256) {
        uint4 u = srow[c];
        unsigned int w[4] = {u.x, u.y, u.z, u.w};
        float a[8];
#pragma unroll
        for (int qq = 0; qq < 4; qq++) {
            float v0 = __uint_as_float(w[qq] << 16);
            float v1 = __uint_as_float(w[qq] & 0xFFFF0000u);
            a[2 * qq]     = (v0 >= t) ? __expf(10.f * v0 - M) * iD : 0.f;
            a[2 * qq + 1] = (v1 >= t) ? __expf(10.f * v1 - M) * iD : 0.f;
        }
        int d0 = __builtin_amdgcn_cvt_pk_fp8_f32(a[0], a[1], 0, false);
        d0     = __builtin_amdgcn_cvt_pk_fp8_f32(a[2], a[3], d0, true);
        int d1 = __builtin_amdgcn_cvt_pk_fp8_f32(a[4], a[5], 0, false);
        d1     = __builtin_amdgcn_cvt_pk_fp8_f32(a[6], a[7], d1, true);
        *(uint2*)&attn8[(size_t)row * LL + c * 8] = make_uint2((unsigned)d0, (unsigned)d1);
    }
}

// ---- fold: overlap-add gather of bf16 agg, /cnt -> zi ----------------------
__global__ void k_fold(const unsigned short* __restrict__ aggb, float* __restrict__ zi) {
    int p = blockIdx.x * 256 + threadIdx.x;
    int x = p & 255, y = (p >> 8) & 255, ci = (p >> 16) & 15, n = p >> 20;
    int yp = y + 1, xp = x + 1;
    int lh1 = yp >> 2; if (lh1 > 63) lh1 = 63;
    int lh0 = (yp >= 3) ? ((yp - 3) >> 2) : 0;
    int lw1 = xp >> 2; if (lw1 > 63) lw1 = 63;
    int lw0 = (xp >= 3) ? ((xp - 3) >> 2) : 0;
    const unsigned short* a0 = aggb + (size_t)n * LL * DINP;
    float sum = 0.f;
    for (int lh = lh0; lh <= lh1; lh++) {
        int dy = yp - 4 * lh;
        for (int lw = lw0; lw <= lw1; lw++) {
            int dx = xp - 4 * lw;
            sum += bf2f(a0[(size_t)(lh * 64 + lw) * DINP + ci * 49 + dy * 7 + dx]);
        }
    }
    float cnt = (float)((lh1 - lh0 + 1) * (lw1 - lw0 + 1));
    zi[p] = sum / cnt;
}

// ---- final: out = b + zi @ W_w^T + W_b -------------------------------------
__global__ void k_final(const float* __restrict__ zi, const float* __restrict__ b,
                        const float* __restrict__ W_w, const float* __restrict__ W_b,
                        float* __restrict__ out) {
    __shared__ float w[16 * 64];
    int tid = threadIdx.x;
    for (int i = tid; i < 16 * 64; i += 256) {
        int ci = i >> 6; int co = i & 63;
        w[i] = W_w[co * 16 + ci];
    }
    __syncthreads();
    int p = blockIdx.x * 256 + tid;
    int n = p >> 16, yx = p & 65535;
    float acc[64];
#pragma unroll
    for (int co = 0; co < 64; co++) acc[co] = 0.f;
    const float* zn = zi + (size_t)n * 16 * 65536;
#pragma unroll
    for (int ci = 0; ci < 16; ci++) {
        float v = zn[ci * 65536 + yx];
#pragma unroll
        for (int co = 0; co < 64; co++) acc[co] += v * w[ci * 64 + co];
    }
    const float* bn = b + (size_t)n * 64 * 65536;
    float* on = out + (size_t)n * 64 * 65536;
#pragma unroll
    for (int co = 0; co < 64; co++) on[co * 65536 + yx] = bn[co * 65536 + yx] + acc[co] + W_b[co];
}

extern "C" void kernel_launch(void* const* d_in, const int* in_sizes, int n_in,
                              void* d_out, int out_size, void* d_ws, size_t ws_size,
                              hipStream_t stream) {
    const float* b     = (const float*)d_in[0];
    const float* g_w   = (const float*)d_in[1];
    const float* g_b   = (const float*)d_in[2];
    const float* th_w  = (const float*)d_in[3];
    const float* th_b  = (const float*)d_in[4];
    const float* W_w   = (const float*)d_in[5];
    const float* W_b   = (const float*)d_in[6];
    const float* fc1_w = (const float*)d_in[7];
    const float* fc1_b = (const float*)d_in[8];
    const float* fc2_w = (const float*)d_in[9];
    const float* fc2_b = (const float*)d_in[10];
    const float* thr_w = (const float*)d_in[11];
    const float* thr_b = (const float*)d_in[12];
    // d_in[13], d_in[14] (bias conv): constant along softmax axis -> cancels.
    float* out = (float*)d_out;

    float* ws = (float*)d_ws;
    size_t off = 0;
    auto alloc = [&](size_t nf) { float* p = ws + off; off += (nf + 63) & ~(size_t)63; return p; };
    unsigned short* aggb = (unsigned short*)alloc((size_t)NB * LL * DINP / 2);
    float* zi   = alloc((size_t)NB * CI * HH * WWD);
    unsigned short* bTp  = (unsigned short*)alloc((size_t)NB * YP * 8 * XP * 8 / 2);
    unsigned short* bx   = (unsigned short*)alloc((size_t)NB * HH * WWD * 32 / 2);
    unsigned short* Pb   = (unsigned short*)alloc((size_t)NB * LL * DKP / 2);
    unsigned char*  piT8 = (unsigned char*)alloc((size_t)NB * DINP * LL / 4);
    unsigned short* fcout = (unsigned short*)alloc((size_t)NB * 2 * LL * DOUTP / 2);
    unsigned short* wbt  = (unsigned short*)alloc(18432 / 2);
    unsigned short* fcwb = (unsigned short*)alloc((size_t)2 * DOUTP * DKP / 2);
    float* thr  = alloc((size_t)NB * LL);
    unsigned short* score = (unsigned short*)alloc((size_t)NB * LL * LL / 2);
    unsigned char*  attn8 = (unsigned char*)alloc((size_t)NB * LL * LL / 4);

    k_prep_b<<<dim3(NB * YP * 8), 256, 0, stream>>>(b, bTp);
    k_prep_wb<<<dim3(72), 256, 0, stream>>>(g_w, th_w, wbt);
    k_prep_fc<<<dim3((2 * DOUTP * DKP + 255) / 256), 256, 0, stream>>>(fc1_w, fc2_w, fcwb);
    k_convm<<<dim3(NB * 256), 256, 0, stream>>>(bTp, wbt, g_b, th_b, bx);
    k_thr<<<dim3(2048), 256, 0, stream>>>(bTp, thr_w, thr_b, thr);
    k_patchesA<<<dim3((int)((size_t)NB * LL * DKP / 256)), 256, 0, stream>>>(bx, Pb);
    k_patchesT<<<dim3((int)((size_t)NB * DINP * LL / 256)), 256, 0, stream>>>(bx, piT8);
    // FC: wif/xif = relu(Pb @ fcwb^T + bias) -> fcout[z=n*2+f][4096][256] bf16
    k_gemm_nt<2><<<dim3(32, 2, 4), 256, 0, stream>>>(
        Pb, fcwb, (void*)fcout, DKP, DKP, DOUTP, DKP,
        (size_t)LL * DKP, (size_t)DOUTP * DKP, (size_t)LL * DOUTP, fc1_b, fc2_b);
    // score[l][m] = wif[l].xif[m]  (bf16 out)
    k_gemm_nt<1><<<dim3(32, 32, NB), 256, 0, stream>>>(
        fcout, fcout + (size_t)LL * DOUTP, (void*)score, DOUTP, DOUTP, LL, DOUTP,
        (size_t)2 * LL * DOUTP, (size_t)2 * LL * DOUTP, (size_t)LL * LL, nullptr, nullptr);
    k_softmax<<<dim3(NB * LL), 256, 0, stream>>>(score, thr, attn8);
    // agg[l][d] = sum_m attn8[l][m] * piT8[d][m]  (MX fp8, unit scale, bf16 out)
    k_gemm_mx<<<dim3(32, DINP / 128, NB), 256, 0, stream>>>(
        attn8, piT8, aggb, LL, LL, DINP, LL,
        (size_t)LL * LL, (size_t)DINP * LL, (size_t)LL * DINP);
    k_fold<<<dim3(8192), 256, 0, stream>>>(aggb, zi);
    k_final<<<dim3(512), 256, 0, stream>>>(zi, b, W_w, W_b, out);
}